// Round 3
// baseline (1692.575 us; speedup 1.0000x reference)
//
#include <hip/hip_runtime.h>

typedef unsigned short u16;
typedef unsigned int u32;
typedef short bf16x8 __attribute__((ext_vector_type(8)));
typedef float f32x4 __attribute__((ext_vector_type(4)));

__device__ __forceinline__ float bf2f(u16 u) {
  u32 x = ((u32)u) << 16;
  float f;
  __builtin_memcpy(&f, &x, 4);
  return f;
}
__device__ __forceinline__ u16 f2bf(float f) {
  u32 x;
  __builtin_memcpy(&x, &f, 4);
  u32 r = x + 0x7FFFu + ((x >> 16) & 1u);
  return (u16)(r >> 16);
}
// async global->LDS, 16B per lane. LDS dest must be wave-uniform base + lane*16.
__device__ __forceinline__ void glds16(const u16* g, u16* l) {
  __builtin_amdgcn_global_load_lds((const __attribute__((address_space(1))) u32*)g,
                                   (__attribute__((address_space(3))) u32*)l, 16, 0, 0);
}

// ---------------- geometry ----------------
// levels: W {256,128,64,32,16} H {160,80,40,20,10}; padded (W+2)x(H+2) NHWC bf16
// padded pixel bases {0, 41796, 52456, 55228, 55976}; total 56192 px
// per-tower activation stride = 56192*256 = 14,385,152 u16 elements

// ---------------- weight conversion ----------------
// tower layout per conv: [tap(9)][chunk(8)][mo(2)][g(4)][o(128)][c8(8)]  (589824 elems)
//   -> stage s (0..35) covers blocks 2s,2s+1: contiguous 16384-elem span
// head layout per (chunk,tap): [g(4)][o(MT)][c8(8)]  (MT: cls 96, reg 16, msk 48)
__global__ void convert_weights(const float* __restrict__ cw, const float* __restrict__ rw,
                                const float* __restrict__ mw, const float* __restrict__ pc,
                                const float* __restrict__ pr, const float* __restrict__ pm,
                                const float* __restrict__ pt, u16* __restrict__ dst) {
  int e = blockIdx.x * 256 + threadIdx.x;
  if (e >= 7446528) return;
  float v = 0.f;
  if (e < 7077888) {
    int conv = e / 589824, r = e % 589824;
    int tap = r / 65536;
    int r2 = r & 65535;
    int chunk = r2 >> 13;
    int r3 = r2 & 8191;
    int mo = r3 >> 12;
    int g = (r3 >> 10) & 3;
    int o = mo * 128 + ((r3 >> 3) & 127);
    int c = chunk * 32 + g * 8 + (r3 & 7);
    const float* s = (conv < 4) ? cw : (conv < 8) ? rw : mw;
    int si = conv & 3;
    v = s[((si * 256 + o) * 256 + c) * 9 + tap];
  } else {
    int e2 = e - 7077888;
    if (e2 < 221184) {  // cls head, MT=96 (80 cls + 1 ctr + pad)
      int chunk = e2 / 27648, r = e2 % 27648;
      int tap = r / 3072, r2 = r % 3072;
      int g = r2 / 768;
      int o = (r2 - g * 768) >> 3;
      int c = chunk * 32 + g * 8 + (r2 & 7);
      if (o < 80) v = pc[(o * 256 + c) * 9 + tap];
      else if (o == 80) v = pt[c * 9 + tap];
    } else if (e2 < 258048) {  // reg head, MT=16
      int e3 = e2 - 221184;
      int chunk = e3 / 4608, r = e3 % 4608;
      int tap = r / 512, r2 = r % 512;
      int g = r2 >> 7;
      int o = (r2 >> 3) & 15;
      int c = chunk * 32 + g * 8 + (r2 & 7);
      if (o < 4) v = pr[(o * 256 + c) * 9 + tap];
    } else {  // msk head, MT=48
      int e3 = e2 - 258048;
      int chunk = e3 / 13824, r = e3 % 13824;
      int tap = r / 1536, r2 = r % 1536;
      int g = r2 / 384;
      int o = (r2 - g * 384) >> 3;
      int c = chunk * 32 + g * 8 + (r2 & 7);
      if (o < 36) v = pm[(o * 256 + c) * 9 + tap];
    }
  }
  dst[e] = f2bf(v);
}

// ---------------- halo zero: clear 1-px border of padded buffers ----------------
// 1632 halo px total across 5 levels; each thread zeroes 16 ch of one (buf,px).
__global__ void halo_zero(u16* __restrict__ X, u16* __restrict__ Y, long ACT, int ntw) {
  int i = blockIdx.x * 256 + threadIdx.x;
  int rep = i / 26112;         // 1632*16
  int j = i - rep * 26112;
  if (rep >= 2 * ntw) return;
  int hp = j >> 4, sub = j & 15;
  int Wp, Hp, pxb, h;
  if (hp < 836)       { Wp = 258; Hp = 162; pxb = 0;     h = hp; }
  else if (hp < 1256) { Wp = 130; Hp = 82;  pxb = 41796; h = hp - 836; }
  else if (hp < 1468) { Wp = 66;  Hp = 42;  pxb = 52456; h = hp - 1256; }
  else if (hp < 1576) { Wp = 34;  Hp = 22;  pxb = 55228; h = hp - 1468; }
  else                { Wp = 18;  Hp = 12;  pxb = 55976; h = hp - 1576; }
  int y, x;
  if (h < Wp)          { y = 0;      x = h; }
  else if (h < 2 * Wp) { y = Hp - 1; x = h - Wp; }
  else {
    int rr = h - 2 * Wp;
    y = 1 + (rr >> 1);
    x = (rr & 1) ? (Wp - 1) : 0;
  }
  u16* buf = (rep < ntw) ? (X + rep * ACT) : (Y + (rep - ntw) * ACT);
  long adr = (long)(pxb + y * Wp + x) * 256 + sub * 16;
  uint4 z = {0, 0, 0, 0};
  *(uint4*)(buf + adr) = z;
  *(uint4*)(buf + adr + 8) = z;
}

// ---------------- feat NCHW fp32 -> padded NHWC bf16 (replicated nrep towers) ------
__global__ void feat_to_nhwc(const float* __restrict__ f0, const float* __restrict__ f1,
                             const float* __restrict__ f2, const float* __restrict__ f3,
                             const float* __restrict__ f4, u16* __restrict__ dst,
                             long tstride, int nrep) {
  __shared__ float lds[64 * 65];
  int bx = blockIdx.x;
  int tile = bx >> 2, c0 = (bx & 3) * 64;
  int tl, sh, pxb, npx;
  const float* src;
  if (tile < 640)      { tl = tile;       sh = 8; pxb = 0;     npx = 40960; src = f0; }
  else if (tile < 800) { tl = tile - 640; sh = 7; pxb = 41796; npx = 10240; src = f1; }
  else if (tile < 840) { tl = tile - 800; sh = 6; pxb = 52456; npx = 2560;  src = f2; }
  else if (tile < 850) { tl = tile - 840; sh = 5; pxb = 55228; npx = 640;   src = f3; }
  else                 { tl = tile - 850; sh = 4; pxb = 55976; npx = 160;   src = f4; }
  int W = 1 << sh, Wp = W + 2;
  int px0 = tl * 64;
  int t = threadIdx.x;
  {
    int cc = (t >> 6) * 16, px = t & 63;
    bool ok = (px0 + px) < npx;
#pragma unroll
    for (int j = 0; j < 16; ++j) {
      float v = ok ? src[(c0 + cc + j) * npx + px0 + px] : 0.f;
      lds[(cc + j) * 65 + px] = v;
    }
  }
  __syncthreads();
  {
    int px = t >> 2, cL = (t & 3) * 16;
    int pxi = px0 + px;
    if (pxi < npx) {
      int y = pxi >> sh, x = pxi & (W - 1);
      u32 w[8];
#pragma unroll
      for (int j = 0; j < 8; ++j) {
        u16 a = f2bf(lds[(cL + 2 * j) * 65 + px]);
        u16 b = f2bf(lds[(cL + 2 * j + 1) * 65 + px]);
        w[j] = (u32)a | ((u32)b << 16);
      }
      long adr = (long)(pxb + (y + 1) * Wp + (x + 1)) * 256 + c0 + cL;
      uint4 v0 = {w[0], w[1], w[2], w[3]}, v1 = {w[4], w[5], w[6], w[7]};
      for (int r = 0; r < nrep; ++r) {
        *(uint4*)(dst + r * tstride + adr) = v0;
        *(uint4*)(dst + r * tstride + adr + 8) = v1;
      }
    }
  }
}

// ---------------- tower conv: 256->256 3x3, bf16 MFMA implicit GEMM ----------------
// grid = ntow*856; 128 outch x 128 px tile, 4 waves, 4x4 frags each.
// K staged 64-deep per barrier pair: 36 stages x 32 MFMA/wave.
// LDS per K-half: A [g(4)][o(128)][8], B [g(4)][p(128)][8]  (conflict-free, measured 0)
__global__ __launch_bounds__(256, 2) void conv_tower(const u16* __restrict__ Xn, long in_ts,
                                                     const u16* __restrict__ Wt, long wt_ts,
                                                     u16* __restrict__ Yraw, long out_ts,
                                                     float* __restrict__ stats, int st_ts) {
  __shared__ u16 Alds[8192];
  __shared__ u16 Blds[8192];
  __shared__ float sred[32];
  int bx = blockIdx.x;
  int tw = bx / 856, r856 = bx - tw * 856;
  Xn += tw * in_ts; Wt += tw * wt_ts; Yraw += tw * out_ts; stats += tw * st_ts;
  int tile = r856 >> 1, mo = r856 & 1;
  int tloc, W, H, SX, pxb, lvl;
  if (tile < 320)      { lvl = 0; tloc = tile;       W = 256; H = 160; SX = 4; pxb = 0; }
  else if (tile < 400) { lvl = 1; tloc = tile - 320; W = 128; H = 80;  SX = 3; pxb = 41796; }
  else if (tile < 420) { lvl = 2; tloc = tile - 400; W = 64;  H = 40;  SX = 2; pxb = 52456; }
  else if (tile < 426) { lvl = 3; tloc = tile - 420; W = 32;  H = 20;  SX = 1; pxb = 55228; }
  else                 { lvl = 4; tloc = tile - 426; W = 16;  H = 10;  SX = 0; pxb = 55976; }
  int Wp = W + 2;
  int ty = tloc >> SX, txi = tloc & ((1 << SX) - 1);
  int y0 = ty * 8, x0 = txi * 16;
  int t = threadIdx.x, lane = t & 63, wave = t >> 6;
  int wm = wave >> 1, wn = wave & 1;
  int quad = lane >> 4, col = lane & 15;
  bool edge = (y0 + 9 > H + 1);
  // staging map: thread t -> pixel p=(t&127) [row p>>4, col p&15], ch-subgroup gg=t>>7
  int rr = (t & 127) >> 4, cc = t & 15;
  int gg = t >> 7;
  const u16* Xrow = Xn + (long)(pxb + (y0 + rr) * Wp + (x0 + cc)) * 256 + gg * 8;
  const u16* Wb = Wt + mo * 4096 + t * 8;
  int aoff = quad * 1024 + (wm * 64 + col) * 8;
  int boff = quad * 1024 + (wn * 64 + col) * 8;
  f32x4 acc[4][4] = {};
  for (int s = 0; s < 36; ++s) {
    int tap = s >> 2, pr = s & 3;
    int dy = tap / 3, dx = tap - dy * 3;
    const u16* wsrc = Wb + s * 16384;           // [2s] block, mo half
    glds16(wsrc, Alds + t * 8);
    glds16(wsrc + 2048, Alds + t * 8 + 2048);
    glds16(wsrc + 8192, Alds + 4096 + t * 8);   // [2s+1] block
    glds16(wsrc + 8192 + 2048, Alds + 4096 + t * 8 + 2048);
    const u16* xb = Xrow + (dy * Wp + dx) * 256 + pr * 64;
    if (!edge) {
      glds16(xb, Blds + t * 8);
      glds16(xb + 16, Blds + t * 8 + 2048);
      glds16(xb + 32, Blds + 4096 + t * 8);
      glds16(xb + 48, Blds + 4096 + t * 8 + 2048);
    } else {
      int yp = y0 + rr + dy;
      uint4 v0 = {0, 0, 0, 0}, v1 = v0, v2 = v0, v3 = v0;
      if (yp <= H + 1) {
        v0 = *(const uint4*)xb;
        v1 = *(const uint4*)(xb + 16);
        v2 = *(const uint4*)(xb + 32);
        v3 = *(const uint4*)(xb + 48);
      }
      *(uint4*)(Blds + t * 8) = v0;
      *(uint4*)(Blds + t * 8 + 2048) = v1;
      *(uint4*)(Blds + 4096 + t * 8) = v2;
      *(uint4*)(Blds + 4096 + t * 8 + 2048) = v3;
    }
    __syncthreads();
#pragma unroll
    for (int h = 0; h < 2; ++h) {
      bf16x8 a[4];
#pragma unroll
      for (int mi = 0; mi < 4; ++mi) a[mi] = *(const bf16x8*)(Alds + h * 4096 + aoff + mi * 128);
#pragma unroll
      for (int ni = 0; ni < 4; ++ni) {
        bf16x8 b = *(const bf16x8*)(Blds + h * 4096 + boff + ni * 128);
#pragma unroll
        for (int mi = 0; mi < 4; ++mi)
          acc[mi][ni] = __builtin_amdgcn_mfma_f32_16x16x32_bf16(a[mi], b, acc[mi][ni], 0, 0, 0);
      }
    }
    __syncthreads();
  }
  // epilogue: store raw bf16 NHWC + group stats
  if (t < 32) sred[t] = 0.f;
  __syncthreads();
  long pebase = (long)(pxb + (y0 + 1) * Wp + (x0 + col + 1)) * 256;
#pragma unroll
  for (int ni = 0; ni < 4; ++ni) {
    int row = wn * 4 + ni;
    if (y0 + row < H) {
#pragma unroll
      for (int mi = 0; mi < 4; ++mi) {
        f32x4 v = acc[mi][ni];
        int o = mo * 128 + wm * 64 + mi * 16 + quad * 4;
        ushort4 pk;
        pk.x = f2bf(v[0]); pk.y = f2bf(v[1]); pk.z = f2bf(v[2]); pk.w = f2bf(v[3]);
        *(ushort4*)(Yraw + pebase + (long)row * Wp * 256 + o) = pk;
      }
    }
  }
#pragma unroll
  for (int mi = 0; mi < 4; ++mi) {
    float s1 = 0.f, s2 = 0.f;
#pragma unroll
    for (int ni = 0; ni < 4; ++ni) {
      if (y0 + wn * 4 + ni < H) {
        f32x4 v = acc[mi][ni];
#pragma unroll
        for (int r2 = 0; r2 < 4; ++r2) { float f = v[r2]; s1 += f; s2 += f * f; }
      }
    }
#pragma unroll
    for (int m = 1; m < 16; m <<= 1) { s1 += __shfl_xor(s1, m); s2 += __shfl_xor(s2, m); }
    if (col == 0) {
      int g = (wm * 64 + mi * 16 + quad * 4) >> 3;
      atomicAdd(&sred[g * 2], s1);
      atomicAdd(&sred[g * 2 + 1], s2);
    }
  }
  __syncthreads();
  if (t < 32) atomicAdd(&stats[(lvl * 32 + mo * 16 + (t >> 1)) * 2 + (t & 1)], sred[t]);
}

// ---------------- GN + ReLU elementwise, in-place ----------------
__global__ void gn_relu(u16* __restrict__ buf, long tstride,
                        const float* __restrict__ stats, int st_ts,
                        const float* __restrict__ g0, const float* __restrict__ g1,
                        const float* __restrict__ g2, const float* __restrict__ b0,
                        const float* __restrict__ b1, const float* __restrict__ b2) {
  int i = blockIdx.x * 256 + threadIdx.x;
  int tw = i / 1745920;            // 54560*32 per tower
  int j = i - tw * 1745920;
  buf += tw * tstride;
  stats += tw * st_ts;
  const float* gamma = (tw == 0) ? g0 : (tw == 1) ? g1 : g2;
  const float* beta = (tw == 0) ? b0 : (tw == 1) ? b1 : b2;
  int px = j >> 5, cg = j & 31, c0 = cg << 3;
  int lvl, sh, pxb, rem;
  float cnt;
  if (px < 40960)      { lvl = 0; rem = px;         sh = 8; pxb = 0;     cnt = 327680.f; }
  else if (px < 51200) { lvl = 1; rem = px - 40960; sh = 7; pxb = 41796; cnt = 81920.f; }
  else if (px < 53760) { lvl = 2; rem = px - 51200; sh = 6; pxb = 52456; cnt = 20480.f; }
  else if (px < 54400) { lvl = 3; rem = px - 53760; sh = 5; pxb = 55228; cnt = 5120.f; }
  else                 { lvl = 4; rem = px - 54400; sh = 4; pxb = 55976; cnt = 1280.f; }
  int W = 1 << sh;
  int y = rem >> sh, x = rem & (W - 1);
  long adr = (long)(pxb + (y + 1) * (W + 2) + (x + 1)) * 256 + c0;
  uint4 rv = *(const uint4*)(buf + adr);
  float s1 = stats[(lvl * 32 + cg) * 2], s2 = stats[(lvl * 32 + cg) * 2 + 1];
  float mean = s1 / cnt;
  float var = s2 / cnt - mean * mean;
  float inv = rsqrtf(fmaxf(var, 0.f) + 1e-5f);
  u32 w[4] = {rv.x, rv.y, rv.z, rv.w};
  u32 ow[4];
#pragma unroll
  for (int jj = 0; jj < 4; ++jj) {
    float v0 = bf2f((u16)(w[jj] & 0xffff));
    float v1 = bf2f((u16)(w[jj] >> 16));
    int c = c0 + 2 * jj;
    v0 = fmaxf((v0 - mean) * inv * gamma[c] + beta[c], 0.f);
    v1 = fmaxf((v1 - mean) * inv * gamma[c + 1] + beta[c + 1], 0.f);
    ow[jj] = (u32)f2bf(v0) | ((u32)f2bf(v1) << 16);
  }
  uint4 sv = {ow[0], ow[1], ow[2], ow[3]};
  *(uint4*)(buf + adr) = sv;
}

// ---------------- fused head conv: all 3 heads in one dispatch ----------------
// ht 0: cls(80)+ctr(1) MT=96; ht 1: reg(4,exp*sb) MT=16; ht 2: msk(36,exp*sm) MT=48
// htsel >= 0 forces a single head (fallback path); htsel < 0: ht = bx/853.
__global__ __launch_bounds__(256, 2) void conv_head_fused(
    const u16* __restrict__ Xbase, long ACT, int htsel, const u16* __restrict__ Whead,
    float* __restrict__ out, const float* __restrict__ pcb, const float* __restrict__ ptb,
    const float* __restrict__ prb, const float* __restrict__ pmb,
    const float* __restrict__ sb, const float* __restrict__ sm) {
  __shared__ u16 Alds[3072];
  __shared__ u16 Blds[2048];
  int bx = blockIdx.x;
  int ht, r;
  if (htsel >= 0) { ht = htsel; r = bx; }
  else { ht = bx / 853; r = bx - ht * 853; }
  int mt, woff;
  const float* bias0;
  const float* scl;
  if (ht == 0)      { mt = 96; woff = 0;      bias0 = pcb; scl = sb; }
  else if (ht == 1) { mt = 16; woff = 221184; bias0 = prb; scl = sb; }
  else              { mt = 48; woff = 258048; bias0 = pmb; scl = sm; }
  const u16* Xn = Xbase + ((htsel >= 0) ? 0 : (long)ht * ACT);
  const u16* Wh = Whead + woff;
  int mt32 = mt * 32, MI = mt >> 4;
  int lvl, tloc, W, H, SX, pxb, npx;
  if (r < 640)      { lvl = 0; tloc = r;       W = 256; H = 160; SX = 4; pxb = 0;     npx = 40960; }
  else if (r < 800) { lvl = 1; tloc = r - 640; W = 128; H = 80;  SX = 3; pxb = 41796; npx = 10240; }
  else if (r < 840) { lvl = 2; tloc = r - 800; W = 64;  H = 40;  SX = 2; pxb = 52456; npx = 2560;  }
  else if (r < 850) { lvl = 3; tloc = r - 840; W = 32;  H = 20;  SX = 1; pxb = 55228; npx = 640;   }
  else              { lvl = 4; tloc = r - 850; W = 16;  H = 10;  SX = 0; pxb = 55976; npx = 160;   }
  int obm, obc = 0;
  if (ht == 0) {
    const int obms[5] = {0, 3276800, 4096000, 4300800, 4352000};
    const int obcs[5] = {4583040, 4624000, 4634240, 4636800, 4637440};
    obm = obms[lvl]; obc = obcs[lvl];
  } else if (ht == 1) {
    const int obms[5] = {4364800, 4528640, 4569600, 4579840, 4582400};
    obm = obms[lvl];
  } else {
    const int obms[5] = {4637600, 6112160, 6480800, 6572960, 6596000};
    obm = obms[lvl];
  }
  int Wp = W + 2;
  int ty = tloc >> SX, txi = tloc & ((1 << SX) - 1);
  int y0 = ty * 4, x0 = txi * 16;
  int t = threadIdx.x, lane = t & 63, wave = t >> 6;
  int quad = lane >> 4, col = lane & 15;
  bool edge = (y0 + 5 > H + 1);
  int rr = (t & 63) >> 4, cc = t & 15, gg = t >> 6;
  const u16* Xrow = Xn + (long)(pxb + (y0 + rr) * Wp + (x0 + cc)) * 256 + gg * 8;
  int aoff = quad * (mt * 8) + col * 8;
  int boff = quad * 512 + (wave * 16 + col) * 8;
  f32x4 acc[6] = {};
  for (int ch = 0; ch < 8; ++ch) {
#pragma unroll
    for (int tap = 0; tap < 9; ++tap) {
      int dy = tap / 3, dx = tap - dy * 3;
      const u16* ws = Wh + (ch * 9 + tap) * mt32;
      int ta = t * 8;
      if (ta < mt32) glds16(ws + ta, Alds + ta);
      int tb = ta + 2048;
      if (tb < mt32) glds16(ws + tb, Alds + tb);
      const u16* xsrc = Xrow + ch * 32 + (dy * Wp + dx) * 256;
      if (!edge) {
        glds16(xsrc, Blds + t * 8);
      } else {
        int yp = y0 + rr + dy;
        uint4 v = {0, 0, 0, 0};
        if (yp <= H + 1) v = *(const uint4*)xsrc;
        *(uint4*)(Blds + t * 8) = v;
      }
      __syncthreads();
      bf16x8 b = *(const bf16x8*)(Blds + boff);
#pragma unroll
      for (int mi = 0; mi < 6; ++mi) {
        if (mi < MI) {
          bf16x8 a = *(const bf16x8*)(Alds + aoff + mi * 128);
          acc[mi] = __builtin_amdgcn_mfma_f32_16x16x32_bf16(a, b, acc[mi], 0, 0, 0);
        }
      }
      __syncthreads();
    }
  }
  int y = y0 + wave;
  if (y < H) {
    float sc = scl[lvl];
    int x = x0 + col;
#pragma unroll
    for (int mi = 0; mi < 6; ++mi) {
      if (mi < MI) {
#pragma unroll
        for (int r2 = 0; r2 < 4; ++r2) {
          int o = mi * 16 + quad * 4 + r2;
          float v = acc[mi][r2];
          if (ht == 0) {
            if (o < 80) out[obm + o * npx + y * W + x] = v + bias0[o];
            else if (o == 80) out[obc + y * W + x] = v + ptb[0];
          } else if (ht == 1) {
            if (o < 4) out[obm + o * npx + y * W + x] = expf((v + bias0[o]) * sc);
          } else {
            if (o < 36) out[obm + o * npx + y * W + x] = expf((v + bias0[o]) * sc);
          }
        }
      }
    }
  }
}

extern "C" void kernel_launch(void* const* d_in, const int* in_sizes, int n_in,
                              void* d_out, int out_size, void* d_ws, size_t ws_size,
                              hipStream_t stream) {
  const float* feat0 = (const float*)d_in[0];
  const float* feat1 = (const float*)d_in[1];
  const float* feat2 = (const float*)d_in[2];
  const float* feat3 = (const float*)d_in[3];
  const float* feat4 = (const float*)d_in[4];
  const float* cw = (const float*)d_in[5];
  const float* rw = (const float*)d_in[8];
  const float* mw = (const float*)d_in[11];
  const float* gmas[3] = {(const float*)d_in[6], (const float*)d_in[9], (const float*)d_in[12]};
  const float* btas[3] = {(const float*)d_in[7], (const float*)d_in[10], (const float*)d_in[13]};
  const float* pcw = (const float*)d_in[14];
  const float* pcb = (const float*)d_in[15];
  const float* prw = (const float*)d_in[16];
  const float* prb = (const float*)d_in[17];
  const float* pmw = (const float*)d_in[18];
  const float* pmb = (const float*)d_in[19];
  const float* ptw = (const float*)d_in[20];
  const float* ptb = (const float*)d_in[21];
  const float* sb = (const float*)d_in[22];
  const float* sm = (const float*)d_in[23];
  float* out = (float*)d_out;

  const long ACT = 14385152;         // u16 elems per tower activation buffer
  const long ACTB = 28770304;        // bytes
  char* base = (char*)d_ws;
  u16* wts = (u16*)base;             // 14,893,056 B

  size_t need_fused = 14893056 + 2 * 3 * (size_t)ACTB + 3840;  // 187,518,720 B

  convert_weights<<<29088, 256, 0, stream>>>(cw, rw, mw, pcw, prw, pmw, ptw, wts);

  if (ws_size >= need_fused) {
    // -------- fused path: all 3 towers per dispatch --------
    u16* X = (u16*)(base + 14893056);               // 3 towers
    u16* Y = (u16*)(base + 14893056 + 3 * ACTB);    // 3 towers
    float* stats = (float*)(base + 14893056 + 6 * ACTB);
    halo_zero<<<612, 256, 0, stream>>>(X, Y, ACT, 3);
    feat_to_nhwc<<<3412, 256, 0, stream>>>(feat0, feat1, feat2, feat3, feat4, X, ACT, 3);
    for (int s = 0; s < 4; ++s) {
      u16* in = (s & 1) ? Y : X;
      u16* ot = (s & 1) ? X : Y;
      hipMemsetAsync(stats, 0, 3840, stream);
      conv_tower<<<2568, 256, 0, stream>>>(in, ACT, wts + s * 589824, 4 * 589824, ot, ACT,
                                           stats, 320);
      gn_relu<<<20460, 256, 0, stream>>>(ot, ACT, stats, 320,
                                         gmas[0] + s * 256, gmas[1] + s * 256, gmas[2] + s * 256,
                                         btas[0] + s * 256, btas[1] + s * 256, btas[2] + s * 256);
    }
    // after s=3 the normalized activations are in X
    conv_head_fused<<<2559, 256, 0, stream>>>(X, ACT, -1, wts + 7077888, out,
                                              pcb, ptb, prb, pmb, sb, sm);
  } else {
    // -------- fallback: sequential towers --------
    u16* bufA = (u16*)(base + 14893056);
    u16* bufB = (u16*)(base + 14893056 + ACTB);
    float* stats = (float*)(base + 14893056 + 2 * ACTB);
    halo_zero<<<204, 256, 0, stream>>>(bufA, bufB, 0, 1);
    for (int tw = 0; tw < 3; ++tw) {
      feat_to_nhwc<<<3412, 256, 0, stream>>>(feat0, feat1, feat2, feat3, feat4, bufA, 0, 1);
      for (int s = 0; s < 4; ++s) {
        u16* in = (s & 1) ? bufB : bufA;
        u16* ot = (s & 1) ? bufA : bufB;
        hipMemsetAsync(stats, 0, 1280, stream);
        conv_tower<<<856, 256, 0, stream>>>(in, 0, wts + (tw * 4 + s) * 589824, 0, ot, 0,
                                            stats, 0);
        gn_relu<<<6820, 256, 0, stream>>>(ot, 0, stats, 0,
                                          gmas[tw] + s * 256, gmas[tw] + s * 256, gmas[tw] + s * 256,
                                          btas[tw] + s * 256, btas[tw] + s * 256, btas[tw] + s * 256);
      }
      conv_head_fused<<<853, 256, 0, stream>>>(bufA, 0, tw, wts + 7077888, out,
                                               pcb, ptb, prb, pmb, sb, sm);
    }
  }
}

// Round 4
// 1202.824 us; speedup vs baseline: 1.4072x; 1.4072x over previous
//
#include <hip/hip_runtime.h>

typedef unsigned short u16;
typedef unsigned int u32;
typedef short bf16x8 __attribute__((ext_vector_type(8)));
typedef float f32x4 __attribute__((ext_vector_type(4)));

__device__ __forceinline__ float bf2f(u16 u) {
  u32 x = ((u32)u) << 16;
  float f;
  __builtin_memcpy(&f, &x, 4);
  return f;
}
__device__ __forceinline__ u16 f2bf(float f) {
  u32 x;
  __builtin_memcpy(&x, &f, 4);
  u32 r = x + 0x7FFFu + ((x >> 16) & 1u);
  return (u16)(r >> 16);
}
// async global->LDS, 16B per lane. LDS dest must be wave-uniform base + lane*16.
__device__ __forceinline__ void glds16(const u16* g, u16* l) {
  __builtin_amdgcn_global_load_lds((const __attribute__((address_space(1))) u32*)g,
                                   (__attribute__((address_space(3))) u32*)l, 16, 0, 0);
}

// ---------------- geometry ----------------
// levels: W {256,128,64,32,16} H {160,80,40,20,10}; padded (W+2)x(H+2) NHWC bf16
// padded pixel bases {0, 41796, 52456, 55228, 55976}; total 56192 px
// per-tower activation stride = 56192*256 = 14,385,152 u16 elements

// ---------------- weight conversion ----------------
// tower layout per conv: [chunk(8)][tap(9)][mo(2)][g(4)][o(128)][c8(8)]  (589824 elems)
// head layout per (chunk,tap): [g(4)][o(MT)][c8(8)]  (MT: cls 96, reg 16, msk 48)
__global__ void convert_weights(const float* __restrict__ cw, const float* __restrict__ rw,
                                const float* __restrict__ mw, const float* __restrict__ pc,
                                const float* __restrict__ pr, const float* __restrict__ pm,
                                const float* __restrict__ pt, u16* __restrict__ dst) {
  int e = blockIdx.x * 256 + threadIdx.x;
  if (e >= 7446528) return;
  float v = 0.f;
  if (e < 7077888) {
    int conv = e / 589824, r = e % 589824;
    int chunk = r / 73728; r %= 73728;
    int tap = r / 8192; r %= 8192;
    int mo = r >> 12;
    int g = (r >> 10) & 3;
    int o = mo * 128 + ((r >> 3) & 127);
    int c = chunk * 32 + g * 8 + (r & 7);
    const float* s = (conv < 4) ? cw : (conv < 8) ? rw : mw;
    int si = conv & 3;
    v = s[((si * 256 + o) * 256 + c) * 9 + tap];
  } else {
    int e2 = e - 7077888;
    if (e2 < 221184) {  // cls head, MT=96 (80 cls + 1 ctr + pad)
      int chunk = e2 / 27648, r = e2 % 27648;
      int tap = r / 3072, r2 = r % 3072;
      int g = r2 / 768;
      int o = (r2 - g * 768) >> 3;
      int c = chunk * 32 + g * 8 + (r2 & 7);
      if (o < 80) v = pc[(o * 256 + c) * 9 + tap];
      else if (o == 80) v = pt[c * 9 + tap];
    } else if (e2 < 258048) {  // reg head, MT=16
      int e3 = e2 - 221184;
      int chunk = e3 / 4608, r = e3 % 4608;
      int tap = r / 512, r2 = r % 512;
      int g = r2 >> 7;
      int o = (r2 >> 3) & 15;
      int c = chunk * 32 + g * 8 + (r2 & 7);
      if (o < 4) v = pr[(o * 256 + c) * 9 + tap];
    } else {  // msk head, MT=48
      int e3 = e2 - 258048;
      int chunk = e3 / 13824, r = e3 % 13824;
      int tap = r / 1536, r2 = r % 1536;
      int g = r2 / 384;
      int o = (r2 - g * 384) >> 3;
      int c = chunk * 32 + g * 8 + (r2 & 7);
      if (o < 36) v = pm[(o * 256 + c) * 9 + tap];
    }
  }
  dst[e] = f2bf(v);
}

// ---------------- halo zero: clear 1-px border of padded buffers ----------------
__global__ void halo_zero(u16* __restrict__ X, u16* __restrict__ Y, long ACT, int ntw) {
  int i = blockIdx.x * 256 + threadIdx.x;
  int rep = i / 26112;         // 1632*16
  int j = i - rep * 26112;
  if (rep >= 2 * ntw) return;
  int hp = j >> 4, sub = j & 15;
  int Wp, Hp, pxb, h;
  if (hp < 836)       { Wp = 258; Hp = 162; pxb = 0;     h = hp; }
  else if (hp < 1256) { Wp = 130; Hp = 82;  pxb = 41796; h = hp - 836; }
  else if (hp < 1468) { Wp = 66;  Hp = 42;  pxb = 52456; h = hp - 1256; }
  else if (hp < 1576) { Wp = 34;  Hp = 22;  pxb = 55228; h = hp - 1468; }
  else                { Wp = 18;  Hp = 12;  pxb = 55976; h = hp - 1576; }
  int y, x;
  if (h < Wp)          { y = 0;      x = h; }
  else if (h < 2 * Wp) { y = Hp - 1; x = h - Wp; }
  else {
    int rr = h - 2 * Wp;
    y = 1 + (rr >> 1);
    x = (rr & 1) ? (Wp - 1) : 0;
  }
  u16* buf = (rep < ntw) ? (X + rep * ACT) : (Y + (rep - ntw) * ACT);
  long adr = (long)(pxb + y * Wp + x) * 256 + sub * 16;
  uint4 z = {0, 0, 0, 0};
  *(uint4*)(buf + adr) = z;
  *(uint4*)(buf + adr + 8) = z;
}

// ---------------- feat NCHW fp32 -> padded NHWC bf16 (replicated nrep towers) ------
__global__ void feat_to_nhwc(const float* __restrict__ f0, const float* __restrict__ f1,
                             const float* __restrict__ f2, const float* __restrict__ f3,
                             const float* __restrict__ f4, u16* __restrict__ dst,
                             long tstride, int nrep) {
  __shared__ float lds[64 * 65];
  int bx = blockIdx.x;
  int tile = bx >> 2, c0 = (bx & 3) * 64;
  int tl, sh, pxb, npx;
  const float* src;
  if (tile < 640)      { tl = tile;       sh = 8; pxb = 0;     npx = 40960; src = f0; }
  else if (tile < 800) { tl = tile - 640; sh = 7; pxb = 41796; npx = 10240; src = f1; }
  else if (tile < 840) { tl = tile - 800; sh = 6; pxb = 52456; npx = 2560;  src = f2; }
  else if (tile < 850) { tl = tile - 840; sh = 5; pxb = 55228; npx = 640;   src = f3; }
  else                 { tl = tile - 850; sh = 4; pxb = 55976; npx = 160;   src = f4; }
  int W = 1 << sh, Wp = W + 2;
  int px0 = tl * 64;
  int t = threadIdx.x;
  {
    int cc = (t >> 6) * 16, px = t & 63;
    bool ok = (px0 + px) < npx;
#pragma unroll
    for (int j = 0; j < 16; ++j) {
      float v = ok ? src[(c0 + cc + j) * npx + px0 + px] : 0.f;
      lds[(cc + j) * 65 + px] = v;
    }
  }
  __syncthreads();
  {
    int px = t >> 2, cL = (t & 3) * 16;
    int pxi = px0 + px;
    if (pxi < npx) {
      int y = pxi >> sh, x = pxi & (W - 1);
      u32 w[8];
#pragma unroll
      for (int j = 0; j < 8; ++j) {
        u16 a = f2bf(lds[(cL + 2 * j) * 65 + px]);
        u16 b = f2bf(lds[(cL + 2 * j + 1) * 65 + px]);
        w[j] = (u32)a | ((u32)b << 16);
      }
      long adr = (long)(pxb + (y + 1) * Wp + (x + 1)) * 256 + c0 + cL;
      uint4 v0 = {w[0], w[1], w[2], w[3]}, v1 = {w[4], w[5], w[6], w[7]};
      for (int r = 0; r < nrep; ++r) {
        *(uint4*)(dst + r * tstride + adr) = v0;
        *(uint4*)(dst + r * tstride + adr + 8) = v1;
      }
    }
  }
}

// ---------------- tower conv: 256->256 3x3, bf16 MFMA implicit GEMM ----------------
// grid = ntow*856; 128 outch x 128 px tile, 4 waves, 4x4 frags each.
// B (act) tile 10x18 px x 32 ch staged in LDS ONCE per ch-chunk; 9 taps read shifted
// windows (px stride 40 u16 = 80 B -> uniform bank spread for b128).
// A (weights) 8 KB/tap, double-buffered, prefetched one tap ahead via glds16.
__global__ __launch_bounds__(256, 4) void conv_tower(const u16* __restrict__ Xn, long in_ts,
                                                     const u16* __restrict__ Wt, long wt_ts,
                                                     u16* __restrict__ Yraw, long out_ts,
                                                     float* __restrict__ stats, int st_ts) {
  __shared__ __align__(16) u16 Alds[8192];   // 2 bufs x [g(4)][o(128)][c8(8)]
  __shared__ __align__(16) u16 Btile[7200];  // [py(10)][px(18)] x (32 ch + 8 pad)
  __shared__ float sred[32];
  int bx = blockIdx.x;
  int tw = bx / 856, r856 = bx - tw * 856;
  Xn += tw * in_ts; Wt += tw * wt_ts; Yraw += tw * out_ts; stats += tw * st_ts;
  int tile = r856 >> 1, mo = r856 & 1;
  int tloc, W, H, SX, pxb, lvl;
  if (tile < 320)      { lvl = 0; tloc = tile;       W = 256; H = 160; SX = 4; pxb = 0; }
  else if (tile < 400) { lvl = 1; tloc = tile - 320; W = 128; H = 80;  SX = 3; pxb = 41796; }
  else if (tile < 420) { lvl = 2; tloc = tile - 400; W = 64;  H = 40;  SX = 2; pxb = 52456; }
  else if (tile < 426) { lvl = 3; tloc = tile - 420; W = 32;  H = 20;  SX = 1; pxb = 55228; }
  else                 { lvl = 4; tloc = tile - 426; W = 16;  H = 10;  SX = 0; pxb = 55976; }
  int Wp = W + 2;
  int ty = tloc >> SX, txi = tloc & ((1 << SX) - 1);
  int y0 = ty * 8, x0 = txi * 16;
  int t = threadIdx.x, lane = t & 63, wave = t >> 6;
  int wm = wave >> 1, wn = wave & 1;
  int quad = lane >> 4, col = lane & 15;
  // tile origin in padded coords: (y0, x0) covers padded rows y0..y0+9, cols x0..x0+17
  const u16* Xbase = Xn + (long)(pxb + y0 * Wp + x0) * 256;
  const u16* Wb = Wt + mo * 4096 + t * 8;
  int aoff = quad * 1024 + (wm * 64 + col) * 8;
  int bcol = wn * 2880 + col * 40 + quad * 8;  // + dy*720 + dx*40 per tap, + ni*720 per frag
  // prefetch A(kt=0) into buf 0
  glds16(Wb, Alds + t * 8);
  glds16(Wb + 2048, Alds + t * 8 + 2048);
  f32x4 acc[4][4] = {};
  for (int ch = 0; ch < 8; ++ch) {
    if (ch) __syncthreads();  // all waves done reading previous Btile
    // stage Btile: 720 units of 16 B (180 px x 4), thread t covers units t, t+256, t+512
#pragma unroll
    for (int i = 0; i < 3; ++i) {
      int u = t + i * 256;
      if (u < 720) {
        int p = u >> 2, q = u & 3;
        int py = p / 18, px = p - py * 18;
        uint4 v = *(const uint4*)(Xbase + (long)(py * Wp + px) * 256 + ch * 32 + q * 8);
        *(uint4*)(Btile + p * 40 + q * 8) = v;
      }
    }
#pragma unroll
    for (int tap = 0; tap < 9; ++tap) {
      int kt = ch * 9 + tap;
      int dy = tap / 3, dx = tap - dy * 3;
      __syncthreads();  // A(kt) arrived; Btile writes visible
      if (kt < 71) {    // prefetch A(kt+1) into other buffer
        const u16* wsrc = Wb + (kt + 1) * 8192;
        u16* ab = Alds + ((kt + 1) & 1) * 4096 + t * 8;
        glds16(wsrc, ab);
        glds16(wsrc + 2048, ab + 2048);
      }
      const u16* Ab = Alds + (kt & 1) * 4096;
      bf16x8 a[4];
#pragma unroll
      for (int mi = 0; mi < 4; ++mi) a[mi] = *(const bf16x8*)(Ab + aoff + mi * 128);
      int bb = bcol + dy * 720 + dx * 40;
#pragma unroll
      for (int ni = 0; ni < 4; ++ni) {
        bf16x8 b = *(const bf16x8*)(Btile + bb + ni * 720);
#pragma unroll
        for (int mi = 0; mi < 4; ++mi)
          acc[mi][ni] = __builtin_amdgcn_mfma_f32_16x16x32_bf16(a[mi], b, acc[mi][ni], 0, 0, 0);
      }
    }
  }
  // epilogue: store raw bf16 NHWC + group stats
  if (t < 32) sred[t] = 0.f;
  __syncthreads();
  long pebase = (long)(pxb + (y0 + 1) * Wp + (x0 + col + 1)) * 256;
#pragma unroll
  for (int ni = 0; ni < 4; ++ni) {
    int row = wn * 4 + ni;
    if (y0 + row < H) {
#pragma unroll
      for (int mi = 0; mi < 4; ++mi) {
        f32x4 v = acc[mi][ni];
        int o = mo * 128 + wm * 64 + mi * 16 + quad * 4;
        ushort4 pk;
        pk.x = f2bf(v[0]); pk.y = f2bf(v[1]); pk.z = f2bf(v[2]); pk.w = f2bf(v[3]);
        *(ushort4*)(Yraw + pebase + (long)row * Wp * 256 + o) = pk;
      }
    }
  }
#pragma unroll
  for (int mi = 0; mi < 4; ++mi) {
    float s1 = 0.f, s2 = 0.f;
#pragma unroll
    for (int ni = 0; ni < 4; ++ni) {
      if (y0 + wn * 4 + ni < H) {
        f32x4 v = acc[mi][ni];
#pragma unroll
        for (int r2 = 0; r2 < 4; ++r2) { float f = v[r2]; s1 += f; s2 += f * f; }
      }
    }
#pragma unroll
    for (int m = 1; m < 16; m <<= 1) { s1 += __shfl_xor(s1, m); s2 += __shfl_xor(s2, m); }
    if (col == 0) {
      int g = (wm * 64 + mi * 16 + quad * 4) >> 3;
      atomicAdd(&sred[g * 2], s1);
      atomicAdd(&sred[g * 2 + 1], s2);
    }
  }
  __syncthreads();
  if (t < 32) atomicAdd(&stats[(lvl * 32 + mo * 16 + (t >> 1)) * 2 + (t & 1)], sred[t]);
}

// ---------------- GN + ReLU elementwise, in-place ----------------
__global__ void gn_relu(u16* __restrict__ buf, long tstride,
                        const float* __restrict__ stats, int st_ts,
                        const float* __restrict__ g0, const float* __restrict__ g1,
                        const float* __restrict__ g2, const float* __restrict__ b0,
                        const float* __restrict__ b1, const float* __restrict__ b2) {
  int i = blockIdx.x * 256 + threadIdx.x;
  int tw = i / 1745920;            // 54560*32 per tower
  int j = i - tw * 1745920;
  buf += tw * tstride;
  stats += tw * st_ts;
  const float* gamma = (tw == 0) ? g0 : (tw == 1) ? g1 : g2;
  const float* beta = (tw == 0) ? b0 : (tw == 1) ? b1 : b2;
  int px = j >> 5, cg = j & 31, c0 = cg << 3;
  int lvl, sh, pxb, rem;
  float cnt;
  if (px < 40960)      { lvl = 0; rem = px;         sh = 8; pxb = 0;     cnt = 327680.f; }
  else if (px < 51200) { lvl = 1; rem = px - 40960; sh = 7; pxb = 41796; cnt = 81920.f; }
  else if (px < 53760) { lvl = 2; rem = px - 51200; sh = 6; pxb = 52456; cnt = 20480.f; }
  else if (px < 54400) { lvl = 3; rem = px - 53760; sh = 5; pxb = 55228; cnt = 5120.f; }
  else                 { lvl = 4; rem = px - 54400; sh = 4; pxb = 55976; cnt = 1280.f; }
  int W = 1 << sh;
  int y = rem >> sh, x = rem & (W - 1);
  long adr = (long)(pxb + (y + 1) * (W + 2) + (x + 1)) * 256 + c0;
  uint4 rv = *(const uint4*)(buf + adr);
  float s1 = stats[(lvl * 32 + cg) * 2], s2 = stats[(lvl * 32 + cg) * 2 + 1];
  float mean = s1 / cnt;
  float var = s2 / cnt - mean * mean;
  float inv = rsqrtf(fmaxf(var, 0.f) + 1e-5f);
  u32 w[4] = {rv.x, rv.y, rv.z, rv.w};
  u32 ow[4];
#pragma unroll
  for (int jj = 0; jj < 4; ++jj) {
    float v0 = bf2f((u16)(w[jj] & 0xffff));
    float v1 = bf2f((u16)(w[jj] >> 16));
    int c = c0 + 2 * jj;
    v0 = fmaxf((v0 - mean) * inv * gamma[c] + beta[c], 0.f);
    v1 = fmaxf((v1 - mean) * inv * gamma[c + 1] + beta[c + 1], 0.f);
    ow[jj] = (u32)f2bf(v0) | ((u32)f2bf(v1) << 16);
  }
  uint4 sv = {ow[0], ow[1], ow[2], ow[3]};
  *(uint4*)(buf + adr) = sv;
}

// ---------------- fused head conv: all 3 heads in one dispatch ----------------
// ht 0: cls(80)+ctr(1) MT=96; ht 1: reg(4,exp*sb) MT=16; ht 2: msk(36,exp*sm) MT=48
__global__ __launch_bounds__(256, 2) void conv_head_fused(
    const u16* __restrict__ Xbase, long ACT, int htsel, const u16* __restrict__ Whead,
    float* __restrict__ out, const float* __restrict__ pcb, const float* __restrict__ ptb,
    const float* __restrict__ prb, const float* __restrict__ pmb,
    const float* __restrict__ sb, const float* __restrict__ sm) {
  __shared__ u16 Alds[3072];
  __shared__ u16 Blds[2048];
  int bx = blockIdx.x;
  int ht, r;
  if (htsel >= 0) { ht = htsel; r = bx; }
  else { ht = bx / 853; r = bx - ht * 853; }
  int mt, woff;
  const float* bias0;
  const float* scl;
  if (ht == 0)      { mt = 96; woff = 0;      bias0 = pcb; scl = sb; }
  else if (ht == 1) { mt = 16; woff = 221184; bias0 = prb; scl = sb; }
  else              { mt = 48; woff = 258048; bias0 = pmb; scl = sm; }
  const u16* Xn = Xbase + ((htsel >= 0) ? 0 : (long)ht * ACT);
  const u16* Wh = Whead + woff;
  int mt32 = mt * 32, MI = mt >> 4;
  int lvl, tloc, W, H, SX, pxb, npx;
  if (r < 640)      { lvl = 0; tloc = r;       W = 256; H = 160; SX = 4; pxb = 0;     npx = 40960; }
  else if (r < 800) { lvl = 1; tloc = r - 640; W = 128; H = 80;  SX = 3; pxb = 41796; npx = 10240; }
  else if (r < 840) { lvl = 2; tloc = r - 800; W = 64;  H = 40;  SX = 2; pxb = 52456; npx = 2560;  }
  else if (r < 850) { lvl = 3; tloc = r - 840; W = 32;  H = 20;  SX = 1; pxb = 55228; npx = 640;   }
  else              { lvl = 4; tloc = r - 850; W = 16;  H = 10;  SX = 0; pxb = 55976; npx = 160;   }
  int obm, obc = 0;
  if (ht == 0) {
    const int obms[5] = {0, 3276800, 4096000, 4300800, 4352000};
    const int obcs[5] = {4583040, 4624000, 4634240, 4636800, 4637440};
    obm = obms[lvl]; obc = obcs[lvl];
  } else if (ht == 1) {
    const int obms[5] = {4364800, 4528640, 4569600, 4579840, 4582400};
    obm = obms[lvl];
  } else {
    const int obms[5] = {4637600, 6112160, 6480800, 6572960, 6596000};
    obm = obms[lvl];
  }
  int Wp = W + 2;
  int ty = tloc >> SX, txi = tloc & ((1 << SX) - 1);
  int y0 = ty * 4, x0 = txi * 16;
  int t = threadIdx.x, lane = t & 63, wave = t >> 6;
  int quad = lane >> 4, col = lane & 15;
  bool edge = (y0 + 5 > H + 1);
  int rr = (t & 63) >> 4, cc = t & 15, gg = t >> 6;
  const u16* Xrow = Xn + (long)(pxb + (y0 + rr) * Wp + (x0 + cc)) * 256 + gg * 8;
  int aoff = quad * (mt * 8) + col * 8;
  int boff = quad * 512 + (wave * 16 + col) * 8;
  f32x4 acc[6] = {};
  for (int ch = 0; ch < 8; ++ch) {
#pragma unroll
    for (int tap = 0; tap < 9; ++tap) {
      int dy = tap / 3, dx = tap - dy * 3;
      const u16* ws = Wh + (ch * 9 + tap) * mt32;
      int ta = t * 8;
      if (ta < mt32) glds16(ws + ta, Alds + ta);
      int tb = ta + 2048;
      if (tb < mt32) glds16(ws + tb, Alds + tb);
      const u16* xsrc = Xrow + ch * 32 + (dy * Wp + dx) * 256;
      if (!edge) {
        glds16(xsrc, Blds + t * 8);
      } else {
        int yp = y0 + rr + dy;
        uint4 v = {0, 0, 0, 0};
        if (yp <= H + 1) v = *(const uint4*)xsrc;
        *(uint4*)(Blds + t * 8) = v;
      }
      __syncthreads();
      bf16x8 b = *(const bf16x8*)(Blds + boff);
#pragma unroll
      for (int mi = 0; mi < 6; ++mi) {
        if (mi < MI) {
          bf16x8 a = *(const bf16x8*)(Alds + aoff + mi * 128);
          acc[mi] = __builtin_amdgcn_mfma_f32_16x16x32_bf16(a, b, acc[mi], 0, 0, 0);
        }
      }
      __syncthreads();
    }
  }
  int y = y0 + wave;
  if (y < H) {
    float sc = scl[lvl];
    int x = x0 + col;
#pragma unroll
    for (int mi = 0; mi < 6; ++mi) {
      if (mi < MI) {
#pragma unroll
        for (int r2 = 0; r2 < 4; ++r2) {
          int o = mi * 16 + quad * 4 + r2;
          float v = acc[mi][r2];
          if (ht == 0) {
            if (o < 80) out[obm + o * npx + y * W + x] = v + bias0[o];
            else if (o == 80) out[obc + y * W + x] = v + ptb[0];
          } else if (ht == 1) {
            if (o < 4) out[obm + o * npx + y * W + x] = expf((v + bias0[o]) * sc);
          } else {
            if (o < 36) out[obm + o * npx + y * W + x] = expf((v + bias0[o]) * sc);
          }
        }
      }
    }
  }
}

extern "C" void kernel_launch(void* const* d_in, const int* in_sizes, int n_in,
                              void* d_out, int out_size, void* d_ws, size_t ws_size,
                              hipStream_t stream) {
  const float* feat0 = (const float*)d_in[0];
  const float* feat1 = (const float*)d_in[1];
  const float* feat2 = (const float*)d_in[2];
  const float* feat3 = (const float*)d_in[3];
  const float* feat4 = (const float*)d_in[4];
  const float* cw = (const float*)d_in[5];
  const float* rw = (const float*)d_in[8];
  const float* mw = (const float*)d_in[11];
  const float* gmas[3] = {(const float*)d_in[6], (const float*)d_in[9], (const float*)d_in[12]};
  const float* btas[3] = {(const float*)d_in[7], (const float*)d_in[10], (const float*)d_in[13]};
  const float* pcw = (const float*)d_in[14];
  const float* pcb = (const float*)d_in[15];
  const float* prw = (const float*)d_in[16];
  const float* prb = (const float*)d_in[17];
  const float* pmw = (const float*)d_in[18];
  const float* pmb = (const float*)d_in[19];
  const float* ptw = (const float*)d_in[20];
  const float* ptb = (const float*)d_in[21];
  const float* sb = (const float*)d_in[22];
  const float* sm = (const float*)d_in[23];
  float* out = (float*)d_out;

  const long ACT = 14385152;         // u16 elems per tower activation buffer
  const long ACTB = 28770304;        // bytes
  char* base = (char*)d_ws;
  u16* wts = (u16*)base;             // 14,893,056 B

  // +64 KB slack: conv_tower B-tile staging may read up to ~55 KB past the last
  // level of the last buffer (discarded rows of edge tiles).
  size_t need_fused = 14893056 + 6 * (size_t)ACTB + 3840 + 65536;

  convert_weights<<<29088, 256, 0, stream>>>(cw, rw, mw, pcw, prw, pmw, ptw, wts);

  if (ws_size >= need_fused) {
    // -------- fused path: all 3 towers per dispatch --------
    u16* X = (u16*)(base + 14893056);               // 3 towers
    u16* Y = (u16*)(base + 14893056 + 3 * ACTB);    // 3 towers
    float* stats = (float*)(base + 14893056 + 6 * ACTB);
    halo_zero<<<612, 256, 0, stream>>>(X, Y, ACT, 3);
    feat_to_nhwc<<<3412, 256, 0, stream>>>(feat0, feat1, feat2, feat3, feat4, X, ACT, 3);
    for (int s = 0; s < 4; ++s) {
      u16* in = (s & 1) ? Y : X;
      u16* ot = (s & 1) ? X : Y;
      hipMemsetAsync(stats, 0, 3840, stream);
      conv_tower<<<2568, 256, 0, stream>>>(in, ACT, wts + s * 589824, 4 * 589824, ot, ACT,
                                           stats, 320);
      gn_relu<<<20460, 256, 0, stream>>>(ot, ACT, stats, 320,
                                         gmas[0] + s * 256, gmas[1] + s * 256, gmas[2] + s * 256,
                                         btas[0] + s * 256, btas[1] + s * 256, btas[2] + s * 256);
    }
    // after s=3 the normalized activations are in X
    conv_head_fused<<<2559, 256, 0, stream>>>(X, ACT, -1, wts + 7077888, out,
                                              pcb, ptb, prb, pmb, sb, sm);
  } else {
    // -------- fallback: sequential towers --------
    u16* bufA = (u16*)(base + 14893056);
    u16* bufB = (u16*)(base + 14893056 + ACTB);
    float* stats = (float*)(base + 14893056 + 2 * ACTB);
    halo_zero<<<204, 256, 0, stream>>>(bufA, bufB, 0, 1);
    for (int tw = 0; tw < 3; ++tw) {
      feat_to_nhwc<<<3412, 256, 0, stream>>>(feat0, feat1, feat2, feat3, feat4, bufA, 0, 1);
      for (int s = 0; s < 4; ++s) {
        u16* in = (s & 1) ? bufB : bufA;
        u16* ot = (s & 1) ? bufA : bufB;
        hipMemsetAsync(stats, 0, 1280, stream);
        conv_tower<<<856, 256, 0, stream>>>(in, 0, wts + (tw * 4 + s) * 589824, 0, ot, 0,
                                            stats, 0);
        gn_relu<<<6820, 256, 0, stream>>>(ot, 0, stats, 0,
                                          gmas[tw] + s * 256, gmas[tw] + s * 256, gmas[tw] + s * 256,
                                          btas[tw] + s * 256, btas[tw] + s * 256, btas[tw] + s * 256);
      }
      conv_head_fused<<<853, 256, 0, stream>>>(bufA, 0, tw, wts + 7077888, out,
                                               pcb, ptb, prb, pmb, sb, sm);
    }
  }
}

// Round 5
// 1145.607 us; speedup vs baseline: 1.4774x; 1.0499x over previous
//
#include <hip/hip_runtime.h>

typedef unsigned short u16;
typedef unsigned int u32;
typedef short bf16x8 __attribute__((ext_vector_type(8)));
typedef float f32x4 __attribute__((ext_vector_type(4)));

__device__ __forceinline__ float bf2f(u16 u) {
  u32 x = ((u32)u) << 16;
  float f;
  __builtin_memcpy(&f, &x, 4);
  return f;
}
__device__ __forceinline__ u16 f2bf(float f) {
  u32 x;
  __builtin_memcpy(&x, &f, 4);
  u32 r = x + 0x7FFFu + ((x >> 16) & 1u);
  return (u16)(r >> 16);
}
// async global->LDS, 16B per lane. LDS dest must be wave-uniform base + lane*16.
__device__ __forceinline__ void glds16(const u16* g, u16* l) {
  __builtin_amdgcn_global_load_lds((const __attribute__((address_space(1))) u32*)g,
                                   (__attribute__((address_space(3))) u32*)l, 16, 0, 0);
}

// ---------------- geometry ----------------
// levels: W {256,128,64,32,16} H {160,80,40,20,10}; padded (W+2)x(H+2) NHWC bf16
// padded pixel bases {0, 41796, 52456, 55228, 55976}; total 56192 px
// per-tower activation stride = 56192*256 = 14,385,152 u16 elements

// ---------------- weight conversion ----------------
// tower layout per conv (A-fragment order, for direct global->reg loads):
//   [mo(2)][kt(72)][wm(2)][mi(4)][lane(64)][j(8)]  (589824 elems)
//   element = W[o = mo*128+wm*64+mi*16+(lane&15)][c = (kt/9)*32+(lane>>4)*8+j][tap = kt%9]
// head layout per (chunk,tap): [g(4)][o(MT)][c8(8)]  (MT: cls 96, reg 16, msk 48)
__global__ void convert_weights(const float* __restrict__ cw, const float* __restrict__ rw,
                                const float* __restrict__ mw, const float* __restrict__ pc,
                                const float* __restrict__ pr, const float* __restrict__ pm,
                                const float* __restrict__ pt, u16* __restrict__ dst) {
  int e = blockIdx.x * 256 + threadIdx.x;
  if (e >= 7446528) return;
  float v = 0.f;
  if (e < 7077888) {
    int conv = e / 589824, r = e % 589824;
    int mo = r / 294912;
    int r2 = r - mo * 294912;
    int kt = r2 >> 12;
    int r3 = r2 & 4095;
    int wm = r3 >> 11;
    int mi = (r3 >> 9) & 3;
    int l = (r3 >> 3) & 63;
    int j = r3 & 7;
    int ch = kt / 9, tap = kt - ch * 9;
    int o = mo * 128 + wm * 64 + mi * 16 + (l & 15);
    int c = ch * 32 + (l >> 4) * 8 + j;
    const float* s = (conv < 4) ? cw : (conv < 8) ? rw : mw;
    int si = conv & 3;
    v = s[((si * 256 + o) * 256 + c) * 9 + tap];
  } else {
    int e2 = e - 7077888;
    if (e2 < 221184) {  // cls head, MT=96 (80 cls + 1 ctr + pad)
      int chunk = e2 / 27648, r = e2 % 27648;
      int tap = r / 3072, r2 = r % 3072;
      int g = r2 / 768;
      int o = (r2 - g * 768) >> 3;
      int c = chunk * 32 + g * 8 + (r2 & 7);
      if (o < 80) v = pc[(o * 256 + c) * 9 + tap];
      else if (o == 80) v = pt[c * 9 + tap];
    } else if (e2 < 258048) {  // reg head, MT=16
      int e3 = e2 - 221184;
      int chunk = e3 / 4608, r = e3 % 4608;
      int tap = r / 512, r2 = r % 512;
      int g = r2 >> 7;
      int o = (r2 >> 3) & 15;
      int c = chunk * 32 + g * 8 + (r2 & 7);
      if (o < 4) v = pr[(o * 256 + c) * 9 + tap];
    } else {  // msk head, MT=48
      int e3 = e2 - 258048;
      int chunk = e3 / 13824, r = e3 % 13824;
      int tap = r / 1536, r2 = r % 1536;
      int g = r2 / 384;
      int o = (r2 - g * 384) >> 3;
      int c = chunk * 32 + g * 8 + (r2 & 7);
      if (o < 36) v = pm[(o * 256 + c) * 9 + tap];
    }
  }
  dst[e] = f2bf(v);
}

// ---------------- halo zero: clear 1-px border of padded buffers ----------------
__global__ void halo_zero(u16* __restrict__ X, u16* __restrict__ Y, long ACT, int ntw) {
  int i = blockIdx.x * 256 + threadIdx.x;
  int rep = i / 26112;         // 1632*16
  int j = i - rep * 26112;
  if (rep >= 2 * ntw) return;
  int hp = j >> 4, sub = j & 15;
  int Wp, Hp, pxb, h;
  if (hp < 836)       { Wp = 258; Hp = 162; pxb = 0;     h = hp; }
  else if (hp < 1256) { Wp = 130; Hp = 82;  pxb = 41796; h = hp - 836; }
  else if (hp < 1468) { Wp = 66;  Hp = 42;  pxb = 52456; h = hp - 1256; }
  else if (hp < 1576) { Wp = 34;  Hp = 22;  pxb = 55228; h = hp - 1468; }
  else                { Wp = 18;  Hp = 12;  pxb = 55976; h = hp - 1576; }
  int y, x;
  if (h < Wp)          { y = 0;      x = h; }
  else if (h < 2 * Wp) { y = Hp - 1; x = h - Wp; }
  else {
    int rr = h - 2 * Wp;
    y = 1 + (rr >> 1);
    x = (rr & 1) ? (Wp - 1) : 0;
  }
  u16* buf = (rep < ntw) ? (X + rep * ACT) : (Y + (rep - ntw) * ACT);
  long adr = (long)(pxb + y * Wp + x) * 256 + sub * 16;
  uint4 z = {0, 0, 0, 0};
  *(uint4*)(buf + adr) = z;
  *(uint4*)(buf + adr + 8) = z;
}

// ---------------- feat NCHW fp32 -> padded NHWC bf16 ----------------
__global__ void feat_to_nhwc(const float* __restrict__ f0, const float* __restrict__ f1,
                             const float* __restrict__ f2, const float* __restrict__ f3,
                             const float* __restrict__ f4, u16* __restrict__ dst,
                             long tstride, int nrep) {
  __shared__ float lds[64 * 65];
  int bx = blockIdx.x;
  int tile = bx >> 2, c0 = (bx & 3) * 64;
  int tl, sh, pxb, npx;
  const float* src;
  if (tile < 640)      { tl = tile;       sh = 8; pxb = 0;     npx = 40960; src = f0; }
  else if (tile < 800) { tl = tile - 640; sh = 7; pxb = 41796; npx = 10240; src = f1; }
  else if (tile < 840) { tl = tile - 800; sh = 6; pxb = 52456; npx = 2560;  src = f2; }
  else if (tile < 850) { tl = tile - 840; sh = 5; pxb = 55228; npx = 640;   src = f3; }
  else                 { tl = tile - 850; sh = 4; pxb = 55976; npx = 160;   src = f4; }
  int W = 1 << sh, Wp = W + 2;
  int px0 = tl * 64;
  int t = threadIdx.x;
  {
    int cc = (t >> 6) * 16, px = t & 63;
    bool ok = (px0 + px) < npx;
#pragma unroll
    for (int j = 0; j < 16; ++j) {
      float v = ok ? src[(c0 + cc + j) * npx + px0 + px] : 0.f;
      lds[(cc + j) * 65 + px] = v;
    }
  }
  __syncthreads();
  {
    int px = t >> 2, cL = (t & 3) * 16;
    int pxi = px0 + px;
    if (pxi < npx) {
      int y = pxi >> sh, x = pxi & (W - 1);
      u32 w[8];
#pragma unroll
      for (int j = 0; j < 8; ++j) {
        u16 a = f2bf(lds[(cL + 2 * j) * 65 + px]);
        u16 b = f2bf(lds[(cL + 2 * j + 1) * 65 + px]);
        w[j] = (u32)a | ((u32)b << 16);
      }
      long adr = (long)(pxb + (y + 1) * Wp + (x + 1)) * 256 + c0 + cL;
      uint4 v0 = {w[0], w[1], w[2], w[3]}, v1 = {w[4], w[5], w[6], w[7]};
      for (int r = 0; r < nrep; ++r) {
        *(uint4*)(dst + r * tstride + adr) = v0;
        *(uint4*)(dst + r * tstride + adr + 8) = v1;
      }
    }
  }
}

// ---------------- finalize GN stats -> per-channel (scale, bias) ----------------
__global__ void finalize_stats(const float* __restrict__ stats, int st_ts,
                               const float* __restrict__ g0, const float* __restrict__ g1,
                               const float* __restrict__ g2, const float* __restrict__ b0,
                               const float* __restrict__ b1, const float* __restrict__ b2,
                               float* __restrict__ scaleb, int sb_ts, int ntw) {
  int i = blockIdx.x * 256 + threadIdx.x;
  if (i >= ntw * 1280) return;
  int tw = i / 1280, r = i - tw * 1280, lvl = r >> 8, c = r & 255, g = c >> 3;
  float cnt = (lvl == 0) ? 327680.f : (lvl == 1) ? 81920.f
              : (lvl == 2) ? 20480.f : (lvl == 3) ? 5120.f : 1280.f;
  float s1 = stats[tw * st_ts + (lvl * 32 + g) * 2];
  float s2 = stats[tw * st_ts + (lvl * 32 + g) * 2 + 1];
  float mean = s1 / cnt;
  float var = s2 / cnt - mean * mean;
  float inv = rsqrtf(fmaxf(var, 0.f) + 1e-5f);
  const float* ga = (tw == 0) ? g0 : (tw == 1) ? g1 : g2;
  const float* be = (tw == 0) ? b0 : (tw == 1) ? b1 : b2;
  float sc = inv * ga[c];
  scaleb[(long)tw * sb_ts + (lvl * 256 + c) * 2] = sc;
  scaleb[(long)tw * sb_ts + (lvl * 256 + c) * 2 + 1] = be[c] - mean * sc;
}

// ---------------- tower conv: 256->256 3x3, bf16 MFMA implicit GEMM ----------------
// 128 o x 128 px block, 4 waves, 4x4 frags. A loaded GLOBAL->registers in exact
// fragment order (no LDS round-trip, no per-tap barrier), double-buffered across taps.
// B: 10x18 px x 32 ch LDS tile per chunk, shared by all 9 taps; optional fused
// GN(scale,bias)+ReLU on staging with halo predicate.
__global__ __launch_bounds__(256, 3) void conv_tower(
    const u16* __restrict__ Xn, long in_ts, const u16* __restrict__ Wt, long wt_ts,
    u16* __restrict__ Yraw, long out_ts, float* __restrict__ stats, int st_ts,
    const float* __restrict__ scaleb, int sb_ts, int do_gn) {
  __shared__ __align__(16) u16 Btile[7200];  // [py*18+px][32ch+8pad]
  __shared__ float shSB[512];                // (scale,bias) per channel
  __shared__ float sred[32];
  int bx = blockIdx.x;
  int tw = bx / 856, r856 = bx - tw * 856;
  Xn += tw * in_ts; Wt += tw * wt_ts; Yraw += tw * out_ts; stats += tw * st_ts;
  int tile = r856 >> 1, mo = r856 & 1;
  int tloc, W, H, SX, pxb, lvl;
  if (tile < 320)      { lvl = 0; tloc = tile;       W = 256; H = 160; SX = 4; pxb = 0; }
  else if (tile < 400) { lvl = 1; tloc = tile - 320; W = 128; H = 80;  SX = 3; pxb = 41796; }
  else if (tile < 420) { lvl = 2; tloc = tile - 400; W = 64;  H = 40;  SX = 2; pxb = 52456; }
  else if (tile < 426) { lvl = 3; tloc = tile - 420; W = 32;  H = 20;  SX = 1; pxb = 55228; }
  else                 { lvl = 4; tloc = tile - 426; W = 16;  H = 10;  SX = 0; pxb = 55976; }
  int Wp = W + 2;
  int ty = tloc >> SX, txi = tloc & ((1 << SX) - 1);
  int y0 = ty * 8, x0 = txi * 16;
  int t = threadIdx.x, lane = t & 63, wave = t >> 6;
  int wm = wave >> 1, wn = wave & 1;
  int quad = lane >> 4, col = lane & 15;
  const u16* Xbase = Xn + (long)(pxb + y0 * Wp + x0) * 256;
  // A fragment base: [mo][kt][wm][mi][lane][8]
  const u16* Wb = Wt + (long)mo * 294912 + wm * 2048 + (long)lane * 8;
  int bcol = wn * 2880 + col * 40 + quad * 8;
  if (do_gn) {
    float2 sv = *(const float2*)(scaleb + (long)tw * sb_ts + (lvl * 256 + t) * 2);
    *(float2*)(&shSB[t * 2]) = sv;
  }
  bf16x8 areg[2][4];
#pragma unroll
  for (int mi = 0; mi < 4; ++mi) areg[0][mi] = *(const bf16x8*)(Wb + mi * 512);
  f32x4 acc[4][4] = {};
  for (int ch = 0; ch < 8; ++ch) {
    __syncthreads();  // shSB ready (ch=0) / all waves done with previous Btile
    // stage Btile: 720 uint4 units; optional GN+ReLU, halo/garbage -> 0
#pragma unroll
    for (int i = 0; i < 3; ++i) {
      int u = t + i * 256;
      if (u < 720) {
        int p = u >> 2, q = u & 3;
        int py = p / 18, px = p - py * 18;
        uint4 v = *(const uint4*)(Xbase + (long)(py * Wp + px) * 256 + ch * 32 + q * 8);
        if (do_gn) {
          int cb = ch * 32 + q * 8;
          int yg = y0 + py, xg = x0 + px;
          bool keep = (yg >= 1) && (yg <= H) && (xg >= 1) && (xg <= W);
          float4 s01 = *(const float4*)(&shSB[cb * 2]);
          float4 s23 = *(const float4*)(&shSB[cb * 2 + 4]);
          float4 s45 = *(const float4*)(&shSB[cb * 2 + 8]);
          float4 s67 = *(const float4*)(&shSB[cb * 2 + 12]);
          u32 wv[4] = {v.x, v.y, v.z, v.w};
          float sc[8] = {s01.x, s01.z, s23.x, s23.z, s45.x, s45.z, s67.x, s67.z};
          float bi[8] = {s01.y, s01.w, s23.y, s23.w, s45.y, s45.w, s67.y, s67.w};
          u32 ow[4];
#pragma unroll
          for (int jj = 0; jj < 4; ++jj) {
            float f0 = bf2f((u16)(wv[jj] & 0xffff)) * sc[2 * jj] + bi[2 * jj];
            float f1 = bf2f((u16)(wv[jj] >> 16)) * sc[2 * jj + 1] + bi[2 * jj + 1];
            f0 = keep ? fmaxf(f0, 0.f) : 0.f;
            f1 = keep ? fmaxf(f1, 0.f) : 0.f;
            ow[jj] = (u32)f2bf(f0) | ((u32)f2bf(f1) << 16);
          }
          v.x = ow[0]; v.y = ow[1]; v.z = ow[2]; v.w = ow[3];
        }
        *(uint4*)(Btile + p * 40 + q * 8) = v;
      }
    }
    __syncthreads();
#pragma unroll
    for (int tap = 0; tap < 9; ++tap) {
      int kt = ch * 9 + tap;
      if (kt < 71) {  // prefetch A(kt+1) -> other register buffer
        const u16* wn_ = Wb + (long)(kt + 1) * 4096;
#pragma unroll
        for (int mi = 0; mi < 4; ++mi)
          areg[(tap + 1) & 1][mi] = *(const bf16x8*)(wn_ + mi * 512);
      }
      int dy = tap / 3, dx = tap - dy * 3;
      int bb = bcol + dy * 720 + dx * 40;
#pragma unroll
      for (int ni = 0; ni < 4; ++ni) {
        bf16x8 b = *(const bf16x8*)(Btile + bb + ni * 720);
#pragma unroll
        for (int mi = 0; mi < 4; ++mi)
          acc[mi][ni] =
              __builtin_amdgcn_mfma_f32_16x16x32_bf16(areg[tap & 1][mi], b, acc[mi][ni], 0, 0, 0);
      }
    }
#pragma unroll
    for (int mi = 0; mi < 4; ++mi) areg[0][mi] = areg[1][mi];  // carry to next chunk
  }
  // epilogue: store raw bf16 NHWC + group stats
  if (t < 32) sred[t] = 0.f;
  __syncthreads();
  long pebase = (long)(pxb + (y0 + 1) * Wp + (x0 + col + 1)) * 256;
#pragma unroll
  for (int ni = 0; ni < 4; ++ni) {
    int row = wn * 4 + ni;
    if (y0 + row < H) {
#pragma unroll
      for (int mi = 0; mi < 4; ++mi) {
        f32x4 v = acc[mi][ni];
        int o = mo * 128 + wm * 64 + mi * 16 + quad * 4;
        ushort4 pk;
        pk.x = f2bf(v[0]); pk.y = f2bf(v[1]); pk.z = f2bf(v[2]); pk.w = f2bf(v[3]);
        *(ushort4*)(Yraw + pebase + (long)row * Wp * 256 + o) = pk;
      }
    }
  }
#pragma unroll
  for (int mi = 0; mi < 4; ++mi) {
    float s1 = 0.f, s2 = 0.f;
#pragma unroll
    for (int ni = 0; ni < 4; ++ni) {
      if (y0 + wn * 4 + ni < H) {
        f32x4 v = acc[mi][ni];
#pragma unroll
        for (int r2 = 0; r2 < 4; ++r2) { float f = v[r2]; s1 += f; s2 += f * f; }
      }
    }
#pragma unroll
    for (int m = 1; m < 16; m <<= 1) { s1 += __shfl_xor(s1, m); s2 += __shfl_xor(s2, m); }
    if (col == 0) {
      int g = (wm * 64 + mi * 16 + quad * 4) >> 3;
      atomicAdd(&sred[g * 2], s1);
      atomicAdd(&sred[g * 2 + 1], s2);
    }
  }
  __syncthreads();
  if (t < 32) atomicAdd(&stats[(lvl * 32 + mo * 16 + (t >> 1)) * 2 + (t & 1)], sred[t]);
}

// ---------------- GN + ReLU elementwise via (scale,bias), in-place ----------------
__global__ void gn_relu(u16* __restrict__ buf, long tstride,
                        const float* __restrict__ scaleb, int sb_ts) {
  int i = blockIdx.x * 256 + threadIdx.x;
  int tw = i / 1745920;            // 54560*32 per tower
  int j = i - tw * 1745920;
  buf += tw * tstride;
  const float* sbp = scaleb + (long)tw * sb_ts;
  int px = j >> 5, cg = j & 31, c0 = cg << 3;
  int lvl, sh, pxb, rem;
  if (px < 40960)      { lvl = 0; rem = px;         sh = 8; pxb = 0;     }
  else if (px < 51200) { lvl = 1; rem = px - 40960; sh = 7; pxb = 41796; }
  else if (px < 53760) { lvl = 2; rem = px - 51200; sh = 6; pxb = 52456; }
  else if (px < 54400) { lvl = 3; rem = px - 53760; sh = 5; pxb = 55228; }
  else                 { lvl = 4; rem = px - 54400; sh = 4; pxb = 55976; }
  int W = 1 << sh;
  int y = rem >> sh, x = rem & (W - 1);
  long adr = (long)(pxb + (y + 1) * (W + 2) + (x + 1)) * 256 + c0;
  uint4 rv = *(const uint4*)(buf + adr);
  const float* pc = sbp + (lvl * 256 + c0) * 2;
  float4 q0 = *(const float4*)(pc);
  float4 q1 = *(const float4*)(pc + 4);
  float4 q2 = *(const float4*)(pc + 8);
  float4 q3 = *(const float4*)(pc + 12);
  float sc[8] = {q0.x, q0.z, q1.x, q1.z, q2.x, q2.z, q3.x, q3.z};
  float bi[8] = {q0.y, q0.w, q1.y, q1.w, q2.y, q2.w, q3.y, q3.w};
  u32 w[4] = {rv.x, rv.y, rv.z, rv.w};
  u32 ow[4];
#pragma unroll
  for (int jj = 0; jj < 4; ++jj) {
    float v0 = fmaxf(bf2f((u16)(w[jj] & 0xffff)) * sc[2 * jj] + bi[2 * jj], 0.f);
    float v1 = fmaxf(bf2f((u16)(w[jj] >> 16)) * sc[2 * jj + 1] + bi[2 * jj + 1], 0.f);
    ow[jj] = (u32)f2bf(v0) | ((u32)f2bf(v1) << 16);
  }
  uint4 sv = {ow[0], ow[1], ow[2], ow[3]};
  *(uint4*)(buf + adr) = sv;
}

// ---------------- fused head conv: all 3 heads in one dispatch ----------------
__global__ __launch_bounds__(256, 2) void conv_head_fused(
    const u16* __restrict__ Xbase, long ACT, int htsel, const u16* __restrict__ Whead,
    float* __restrict__ out, const float* __restrict__ pcb, const float* __restrict__ ptb,
    const float* __restrict__ prb, const float* __restrict__ pmb,
    const float* __restrict__ sb, const float* __restrict__ sm) {
  __shared__ u16 Alds[3072];
  __shared__ u16 Blds[2048];
  int bx = blockIdx.x;
  int ht, r;
  if (htsel >= 0) { ht = htsel; r = bx; }
  else { ht = bx / 853; r = bx - ht * 853; }
  int mt, woff;
  const float* bias0;
  const float* scl;
  if (ht == 0)      { mt = 96; woff = 0;      bias0 = pcb; scl = sb; }
  else if (ht == 1) { mt = 16; woff = 221184; bias0 = prb; scl = sb; }
  else              { mt = 48; woff = 258048; bias0 = pmb; scl = sm; }
  const u16* Xn = Xbase + ((htsel >= 0) ? 0 : (long)ht * ACT);
  const u16* Wh = Whead + woff;
  int mt32 = mt * 32, MI = mt >> 4;
  int lvl, tloc, W, H, SX, pxb, npx;
  if (r < 640)      { lvl = 0; tloc = r;       W = 256; H = 160; SX = 4; pxb = 0;     npx = 40960; }
  else if (r < 800) { lvl = 1; tloc = r - 640; W = 128; H = 80;  SX = 3; pxb = 41796; npx = 10240; }
  else if (r < 840) { lvl = 2; tloc = r - 800; W = 64;  H = 40;  SX = 2; pxb = 52456; npx = 2560;  }
  else if (r < 850) { lvl = 3; tloc = r - 840; W = 32;  H = 20;  SX = 1; pxb = 55228; npx = 640;   }
  else              { lvl = 4; tloc = r - 850; W = 16;  H = 10;  SX = 0; pxb = 55976; npx = 160;   }
  int obm, obc = 0;
  if (ht == 0) {
    const int obms[5] = {0, 3276800, 4096000, 4300800, 4352000};
    const int obcs[5] = {4583040, 4624000, 4634240, 4636800, 4637440};
    obm = obms[lvl]; obc = obcs[lvl];
  } else if (ht == 1) {
    const int obms[5] = {4364800, 4528640, 4569600, 4579840, 4582400};
    obm = obms[lvl];
  } else {
    const int obms[5] = {4637600, 6112160, 6480800, 6572960, 6596000};
    obm = obms[lvl];
  }
  int Wp = W + 2;
  int ty = tloc >> SX, txi = tloc & ((1 << SX) - 1);
  int y0 = ty * 4, x0 = txi * 16;
  int t = threadIdx.x, lane = t & 63, wave = t >> 6;
  int quad = lane >> 4, col = lane & 15;
  bool edge = (y0 + 5 > H + 1);
  int rr = (t & 63) >> 4, cc = t & 15, gg = t >> 6;
  const u16* Xrow = Xn + (long)(pxb + (y0 + rr) * Wp + (x0 + cc)) * 256 + gg * 8;
  int aoff = quad * (mt * 8) + col * 8;
  int boff = quad * 512 + (wave * 16 + col) * 8;
  f32x4 acc[6] = {};
  for (int ch = 0; ch < 8; ++ch) {
#pragma unroll
    for (int tap = 0; tap < 9; ++tap) {
      int dy = tap / 3, dx = tap - dy * 3;
      const u16* ws = Wh + (ch * 9 + tap) * mt32;
      int ta = t * 8;
      if (ta < mt32) glds16(ws + ta, Alds + ta);
      int tb = ta + 2048;
      if (tb < mt32) glds16(ws + tb, Alds + tb);
      const u16* xsrc = Xrow + ch * 32 + (dy * Wp + dx) * 256;
      if (!edge) {
        glds16(xsrc, Blds + t * 8);
      } else {
        int yp = y0 + rr + dy;
        uint4 v = {0, 0, 0, 0};
        if (yp <= H + 1) v = *(const uint4*)xsrc;
        *(uint4*)(Blds + t * 8) = v;
      }
      __syncthreads();
      bf16x8 b = *(const bf16x8*)(Blds + boff);
#pragma unroll
      for (int mi = 0; mi < 6; ++mi) {
        if (mi < MI) {
          bf16x8 a = *(const bf16x8*)(Alds + aoff + mi * 128);
          acc[mi] = __builtin_amdgcn_mfma_f32_16x16x32_bf16(a, b, acc[mi], 0, 0, 0);
        }
      }
      __syncthreads();
    }
  }
  int y = y0 + wave;
  if (y < H) {
    float sc = scl[lvl];
    int x = x0 + col;
#pragma unroll
    for (int mi = 0; mi < 6; ++mi) {
      if (mi < MI) {
#pragma unroll
        for (int r2 = 0; r2 < 4; ++r2) {
          int o = mi * 16 + quad * 4 + r2;
          float v = acc[mi][r2];
          if (ht == 0) {
            if (o < 80) out[obm + o * npx + y * W + x] = v + bias0[o];
            else if (o == 80) out[obc + y * W + x] = v + ptb[0];
          } else if (ht == 1) {
            if (o < 4) out[obm + o * npx + y * W + x] = expf((v + bias0[o]) * sc);
          } else {
            if (o < 36) out[obm + o * npx + y * W + x] = expf((v + bias0[o]) * sc);
          }
        }
      }
    }
  }
}

extern "C" void kernel_launch(void* const* d_in, const int* in_sizes, int n_in,
                              void* d_out, int out_size, void* d_ws, size_t ws_size,
                              hipStream_t stream) {
  const float* feat0 = (const float*)d_in[0];
  const float* feat1 = (const float*)d_in[1];
  const float* feat2 = (const float*)d_in[2];
  const float* feat3 = (const float*)d_in[3];
  const float* feat4 = (const float*)d_in[4];
  const float* cw = (const float*)d_in[5];
  const float* rw = (const float*)d_in[8];
  const float* mw = (const float*)d_in[11];
  const float* gmas[3] = {(const float*)d_in[6], (const float*)d_in[9], (const float*)d_in[12]};
  const float* btas[3] = {(const float*)d_in[7], (const float*)d_in[10], (const float*)d_in[13]};
  const float* pcw = (const float*)d_in[14];
  const float* pcb = (const float*)d_in[15];
  const float* prw = (const float*)d_in[16];
  const float* prb = (const float*)d_in[17];
  const float* pmw = (const float*)d_in[18];
  const float* pmb = (const float*)d_in[19];
  const float* ptw = (const float*)d_in[20];
  const float* ptb = (const float*)d_in[21];
  const float* sb = (const float*)d_in[22];
  const float* sm = (const float*)d_in[23];
  float* out = (float*)d_out;

  const long ACT = 14385152;         // u16 elems per tower activation buffer
  const long ACTB = 28770304;        // bytes
  const long WTS = 14893056;         // bytes of converted weights
  char* base = (char*)d_ws;
  u16* wts = (u16*)base;

  // fused layout: wts | X3 (3) | Y3 (3) | stats (3840 B) | scaleb (30720 B) | 64 KB slack
  size_t need_fused = WTS + 6 * (size_t)ACTB + 3840 + 30720 + 65536;

  convert_weights<<<29088, 256, 0, stream>>>(cw, rw, mw, pcw, prw, pmw, ptw, wts);

  if (ws_size >= need_fused) {
    u16* X = (u16*)(base + WTS);
    u16* Y = (u16*)(base + WTS + 3 * ACTB);
    float* stats = (float*)(base + WTS + 6 * ACTB);
    float* scaleb = (float*)(base + WTS + 6 * ACTB + 3840);
    halo_zero<<<612, 256, 0, stream>>>(X, Y, ACT, 3);
    feat_to_nhwc<<<3412, 256, 0, stream>>>(feat0, feat1, feat2, feat3, feat4, X, ACT, 1);
    for (int s = 0; s < 4; ++s) {
      u16* in = (s & 1) ? Y : X;
      u16* ot = (s & 1) ? X : Y;
      long ints = (s == 0) ? 0 : ACT;  // s=0: all towers share the single staged input
      hipMemsetAsync(stats, 0, 3840, stream);
      conv_tower<<<2568, 256, 0, stream>>>(in, ints, wts + s * 589824, 4 * 589824, ot, ACT,
                                           stats, 320, scaleb, 2560, s > 0);
      finalize_stats<<<15, 256, 0, stream>>>(stats, 320,
                                             gmas[0] + s * 256, gmas[1] + s * 256, gmas[2] + s * 256,
                                             btas[0] + s * 256, btas[1] + s * 256, btas[2] + s * 256,
                                             scaleb, 2560, 3);
    }
    // towers s0->Y, s1->X, s2->Y, s3->X; normalize s3 output in X, then heads
    gn_relu<<<20460, 256, 0, stream>>>(X, ACT, scaleb, 2560);
    conv_head_fused<<<2559, 256, 0, stream>>>(X, ACT, -1, wts + 7077888, out,
                                              pcb, ptb, prb, pmb, sb, sm);
  } else {
    // -------- fallback: sequential towers --------
    u16* bufA = (u16*)(base + WTS);
    u16* bufB = (u16*)(base + WTS + ACTB);
    float* stats = (float*)(base + WTS + 2 * ACTB);
    float* scaleb = (float*)(base + WTS + 2 * ACTB + 1280);
    halo_zero<<<204, 256, 0, stream>>>(bufA, bufB, 0, 1);
    for (int tw = 0; tw < 3; ++tw) {
      feat_to_nhwc<<<3412, 256, 0, stream>>>(feat0, feat1, feat2, feat3, feat4, bufA, 0, 1);
      for (int s = 0; s < 4; ++s) {
        u16* in = (s & 1) ? bufB : bufA;
        u16* ot = (s & 1) ? bufA : bufB;
        hipMemsetAsync(stats, 0, 1280, stream);
        conv_tower<<<856, 256, 0, stream>>>(in, 0, wts + (tw * 4 + s) * 589824, 0, ot, 0,
                                            stats, 0, scaleb, 0, s > 0);
        finalize_stats<<<5, 256, 0, stream>>>(stats, 0,
                                              gmas[tw] + s * 256, gmas[tw] + s * 256, gmas[tw] + s * 256,
                                              btas[tw] + s * 256, btas[tw] + s * 256, btas[tw] + s * 256,
                                              scaleb, 0, 1);
      }
      // towers: s0->B, s1->A, s2->B, s3->A
      gn_relu<<<6820, 256, 0, stream>>>(bufA, 0, scaleb, 0);
      conv_head_fused<<<853, 256, 0, stream>>>(bufA, 0, tw, wts + 7077888, out,
                                               pcb, ptb, prb, pmb, sb, sm);
    }
  }
}

// Round 6
// 1129.498 us; speedup vs baseline: 1.4985x; 1.0143x over previous
//
#include <hip/hip_runtime.h>

typedef unsigned short u16;
typedef unsigned int u32;
typedef short bf16x8 __attribute__((ext_vector_type(8)));
typedef float f32x4 __attribute__((ext_vector_type(4)));

__device__ __forceinline__ float bf2f(u16 u) {
  u32 x = ((u32)u) << 16;
  float f;
  __builtin_memcpy(&f, &x, 4);
  return f;
}
__device__ __forceinline__ u16 f2bf(float f) {
  u32 x;
  __builtin_memcpy(&x, &f, 4);
  u32 r = x + 0x7FFFu + ((x >> 16) & 1u);
  return (u16)(r >> 16);
}
// pack two fp32 -> bf16x2 (round-to-nearest-half-up): 2 adds + v_perm
__device__ __forceinline__ u32 pack2(float f0, float f1) {
  u32 a, b;
  __builtin_memcpy(&a, &f0, 4);
  __builtin_memcpy(&b, &f1, 4);
  a += 0x8000u;
  b += 0x8000u;
  return __builtin_amdgcn_perm(b, a, 0x07060302);
}
// async global->LDS, 16B per lane. LDS dest must be wave-uniform base + lane*16.
__device__ __forceinline__ void glds16(const u16* g, u16* l) {
  __builtin_amdgcn_global_load_lds((const __attribute__((address_space(1))) u32*)g,
                                   (__attribute__((address_space(3))) u32*)l, 16, 0, 0);
}

// ---------------- geometry ----------------
// levels: W {256,128,64,32,16} H {160,80,40,20,10}; padded (W+2)x(H+2) NHWC bf16
// padded pixel bases {0, 41796, 52456, 55228, 55976}; total 56192 px
// per-tower activation stride = 56192*256 = 14,385,152 u16 elements

// ---------------- weight conversion ----------------
// tower layout per conv (A-fragment order, for direct global->reg loads):
//   [mo(2)][kt(72)][wm(2)][mi(4)][lane(64)][j(8)]  (589824 elems)
//   element = W[o = mo*128+wm*64+mi*16+(lane&15)][c = (kt/9)*32+(lane>>4)*8+j][tap = kt%9]
// head layout per (chunk,tap): [g(4)][o(MT)][c8(8)]  (MT: cls 96, reg 16, msk 48)
__global__ void convert_weights(const float* __restrict__ cw, const float* __restrict__ rw,
                                const float* __restrict__ mw, const float* __restrict__ pc,
                                const float* __restrict__ pr, const float* __restrict__ pm,
                                const float* __restrict__ pt, u16* __restrict__ dst) {
  int e = blockIdx.x * 256 + threadIdx.x;
  if (e >= 7446528) return;
  float v = 0.f;
  if (e < 7077888) {
    int conv = e / 589824, r = e % 589824;
    int mo = r / 294912;
    int r2 = r - mo * 294912;
    int kt = r2 >> 12;
    int r3 = r2 & 4095;
    int wm = r3 >> 11;
    int mi = (r3 >> 9) & 3;
    int l = (r3 >> 3) & 63;
    int j = r3 & 7;
    int ch = kt / 9, tap = kt - ch * 9;
    int o = mo * 128 + wm * 64 + mi * 16 + (l & 15);
    int c = ch * 32 + (l >> 4) * 8 + j;
    const float* s = (conv < 4) ? cw : (conv < 8) ? rw : mw;
    int si = conv & 3;
    v = s[((si * 256 + o) * 256 + c) * 9 + tap];
  } else {
    int e2 = e - 7077888;
    if (e2 < 221184) {  // cls head, MT=96 (80 cls + 1 ctr + pad)
      int chunk = e2 / 27648, r = e2 % 27648;
      int tap = r / 3072, r2 = r % 3072;
      int g = r2 / 768;
      int o = (r2 - g * 768) >> 3;
      int c = chunk * 32 + g * 8 + (r2 & 7);
      if (o < 80) v = pc[(o * 256 + c) * 9 + tap];
      else if (o == 80) v = pt[c * 9 + tap];
    } else if (e2 < 258048) {  // reg head, MT=16
      int e3 = e2 - 221184;
      int chunk = e3 / 4608, r = e3 % 4608;
      int tap = r / 512, r2 = r % 512;
      int g = r2 >> 7;
      int o = (r2 >> 3) & 15;
      int c = chunk * 32 + g * 8 + (r2 & 7);
      if (o < 4) v = pr[(o * 256 + c) * 9 + tap];
    } else {  // msk head, MT=48
      int e3 = e2 - 258048;
      int chunk = e3 / 13824, r = e3 % 13824;
      int tap = r / 1536, r2 = r % 1536;
      int g = r2 / 384;
      int o = (r2 - g * 384) >> 3;
      int c = chunk * 32 + g * 8 + (r2 & 7);
      if (o < 36) v = pm[(o * 256 + c) * 9 + tap];
    }
  }
  dst[e] = f2bf(v);
}

// ---------------- halo zero: clear 1-px border of padded buffers ----------------
__global__ void halo_zero(u16* __restrict__ X, u16* __restrict__ Y, long ACT, int ntw) {
  int i = blockIdx.x * 256 + threadIdx.x;
  int rep = i / 26112;         // 1632*16
  int j = i - rep * 26112;
  if (rep >= 2 * ntw) return;
  int hp = j >> 4, sub = j & 15;
  int Wp, Hp, pxb, h;
  if (hp < 836)       { Wp = 258; Hp = 162; pxb = 0;     h = hp; }
  else if (hp < 1256) { Wp = 130; Hp = 82;  pxb = 41796; h = hp - 836; }
  else if (hp < 1468) { Wp = 66;  Hp = 42;  pxb = 52456; h = hp - 1256; }
  else if (hp < 1576) { Wp = 34;  Hp = 22;  pxb = 55228; h = hp - 1468; }
  else                { Wp = 18;  Hp = 12;  pxb = 55976; h = hp - 1576; }
  int y, x;
  if (h < Wp)          { y = 0;      x = h; }
  else if (h < 2 * Wp) { y = Hp - 1; x = h - Wp; }
  else {
    int rr = h - 2 * Wp;
    y = 1 + (rr >> 1);
    x = (rr & 1) ? (Wp - 1) : 0;
  }
  u16* buf = (rep < ntw) ? (X + rep * ACT) : (Y + (rep - ntw) * ACT);
  long adr = (long)(pxb + y * Wp + x) * 256 + sub * 16;
  uint4 z = {0, 0, 0, 0};
  *(uint4*)(buf + adr) = z;
  *(uint4*)(buf + adr + 8) = z;
}

// ---------------- feat NCHW fp32 -> padded NHWC bf16 ----------------
__global__ void feat_to_nhwc(const float* __restrict__ f0, const float* __restrict__ f1,
                             const float* __restrict__ f2, const float* __restrict__ f3,
                             const float* __restrict__ f4, u16* __restrict__ dst,
                             long tstride, int nrep) {
  __shared__ float lds[64 * 65];
  int bx = blockIdx.x;
  int tile = bx >> 2, c0 = (bx & 3) * 64;
  int tl, sh, pxb, npx;
  const float* src;
  if (tile < 640)      { tl = tile;       sh = 8; pxb = 0;     npx = 40960; src = f0; }
  else if (tile < 800) { tl = tile - 640; sh = 7; pxb = 41796; npx = 10240; src = f1; }
  else if (tile < 840) { tl = tile - 800; sh = 6; pxb = 52456; npx = 2560;  src = f2; }
  else if (tile < 850) { tl = tile - 840; sh = 5; pxb = 55228; npx = 640;   src = f3; }
  else                 { tl = tile - 850; sh = 4; pxb = 55976; npx = 160;   src = f4; }
  int W = 1 << sh, Wp = W + 2;
  int px0 = tl * 64;
  int t = threadIdx.x;
  {
    int cc = (t >> 6) * 16, px = t & 63;
    bool ok = (px0 + px) < npx;
#pragma unroll
    for (int j = 0; j < 16; ++j) {
      float v = ok ? src[(c0 + cc + j) * npx + px0 + px] : 0.f;
      lds[(cc + j) * 65 + px] = v;
    }
  }
  __syncthreads();
  {
    int px = t >> 2, cL = (t & 3) * 16;
    int pxi = px0 + px;
    if (pxi < npx) {
      int y = pxi >> sh, x = pxi & (W - 1);
      u32 w[8];
#pragma unroll
      for (int j = 0; j < 8; ++j)
        w[j] = pack2(lds[(cL + 2 * j) * 65 + px], lds[(cL + 2 * j + 1) * 65 + px]);
      long adr = (long)(pxb + (y + 1) * Wp + (x + 1)) * 256 + c0 + cL;
      uint4 v0 = {w[0], w[1], w[2], w[3]}, v1 = {w[4], w[5], w[6], w[7]};
      for (int r = 0; r < nrep; ++r) {
        *(uint4*)(dst + r * tstride + adr) = v0;
        *(uint4*)(dst + r * tstride + adr + 8) = v1;
      }
    }
  }
}

// ---------------- finalize GN stats -> per-channel (scale, bias) ----------------
__global__ void finalize_stats(const float* __restrict__ stats, int st_ts,
                               const float* __restrict__ g0, const float* __restrict__ g1,
                               const float* __restrict__ g2, const float* __restrict__ b0,
                               const float* __restrict__ b1, const float* __restrict__ b2,
                               float* __restrict__ scaleb, int sb_ts, int ntw) {
  int i = blockIdx.x * 256 + threadIdx.x;
  if (i >= ntw * 1280) return;
  int tw = i / 1280, r = i - tw * 1280, lvl = r >> 8, c = r & 255, g = c >> 3;
  float cnt = (lvl == 0) ? 327680.f : (lvl == 1) ? 81920.f
              : (lvl == 2) ? 20480.f : (lvl == 3) ? 5120.f : 1280.f;
  float s1 = stats[tw * st_ts + (lvl * 32 + g) * 2];
  float s2 = stats[tw * st_ts + (lvl * 32 + g) * 2 + 1];
  float mean = s1 / cnt;
  float var = s2 / cnt - mean * mean;
  float inv = rsqrtf(fmaxf(var, 0.f) + 1e-5f);
  const float* ga = (tw == 0) ? g0 : (tw == 1) ? g1 : g2;
  const float* be = (tw == 0) ? b0 : (tw == 1) ? b1 : b2;
  float sc = inv * ga[c];
  scaleb[(long)tw * sb_ts + (lvl * 256 + c) * 2] = sc;
  scaleb[(long)tw * sb_ts + (lvl * 256 + c) * 2 + 1] = be[c] - mean * sc;
}

// ---------------- tower conv: 256->256 3x3, bf16 MFMA implicit GEMM ----------------
// 128 o x 128 px block, 4 waves, 4x4 frags. A global->registers in fragment order,
// double-buffered across taps. B: plane-split LDS tile [q(4)][180px][8ch] (2-way banks
// on both write and read = free), staged from registers PREFETCHED one chunk ahead
// (global latency hidden behind the 9-tap MFMA run). Fused GN+ReLU on staging.
__global__ __launch_bounds__(256, 3) void conv_tower(
    const u16* __restrict__ Xn, long in_ts, const u16* __restrict__ Wt, long wt_ts,
    u16* __restrict__ Yraw, long out_ts, float* __restrict__ stats, int st_ts,
    const float* __restrict__ scaleb, int sb_ts, int do_gn) {
  __shared__ __align__(16) u16 Btile[5760];  // 4 planes x 180 px x 8 ch
  __shared__ float shSB[512];                // (scale,bias) per channel
  __shared__ float sred[32];
  int bx = blockIdx.x;
  int tw = bx / 856, r856 = bx - tw * 856;
  Xn += tw * in_ts; Wt += tw * wt_ts; Yraw += tw * out_ts; stats += tw * st_ts;
  int tile = r856 >> 1, mo = r856 & 1;
  int tloc, W, H, SX, pxb, lvl;
  if (tile < 320)      { lvl = 0; tloc = tile;       W = 256; H = 160; SX = 4; pxb = 0; }
  else if (tile < 400) { lvl = 1; tloc = tile - 320; W = 128; H = 80;  SX = 3; pxb = 41796; }
  else if (tile < 420) { lvl = 2; tloc = tile - 400; W = 64;  H = 40;  SX = 2; pxb = 52456; }
  else if (tile < 426) { lvl = 3; tloc = tile - 420; W = 32;  H = 20;  SX = 1; pxb = 55228; }
  else                 { lvl = 4; tloc = tile - 426; W = 16;  H = 10;  SX = 0; pxb = 55976; }
  int Wp = W + 2;
  int ty = tloc >> SX, txi = tloc & ((1 << SX) - 1);
  int y0 = ty * 8, x0 = txi * 16;
  int t = threadIdx.x, lane = t & 63, wave = t >> 6;
  int wm = wave >> 1, wn = wave & 1;
  int quad = lane >> 4, col = lane & 15;
  const u16* Xbase = Xn + (long)(pxb + y0 * Wp + x0) * 256;
  // A fragment base: [mo][kt][wm][mi][lane][8]
  const u16* Wb = Wt + (long)mo * 294912 + wm * 2048 + (long)lane * 8;
  int bcol = quad * 1440 + wn * 576 + col * 8;  // + dy*144 + dx*8 per tap, + ni*144
  if (do_gn) {
    float2 sv = *(const float2*)(scaleb + (long)tw * sb_ts + (lvl * 256 + t) * 2);
    *(float2*)(&shSB[t * 2]) = sv;
  }
  // per-thread staging map: 3 units of (plane q, pixel p)
  const u16* Pptr[3];
  int Lo[3], Cb[3];
  bool Uok[3], Keep[3];
#pragma unroll
  for (int i = 0; i < 3; ++i) {
    int u = t + i * 256;
    Uok[i] = u < 720;
    int q = u & 3, p = u >> 2;
    int py = p / 18, px = p - py * 18;
    Pptr[i] = Xbase + (long)(py * Wp + px) * 256 + q * 8;
    Lo[i] = q * 1440 + p * 8;
    Cb[i] = q * 8;
    int yg = y0 + py, xg = x0 + px;
    Keep[i] = (yg >= 1) && (yg <= H) && (xg >= 1) && (xg <= W);
  }
  uint4 breg[3];
#pragma unroll
  for (int i = 0; i < 3; ++i)
    if (Uok[i]) breg[i] = *(const uint4*)(Pptr[i]);  // ch=0 staging data
  bf16x8 areg[2][4];
#pragma unroll
  for (int mi = 0; mi < 4; ++mi) areg[0][mi] = *(const bf16x8*)(Wb + mi * 512);
  f32x4 acc[4][4] = {};
  for (int ch = 0; ch < 8; ++ch) {
    __syncthreads();  // shSB ready (ch=0) / all waves done reading previous Btile
#pragma unroll
    for (int i = 0; i < 3; ++i) {
      if (Uok[i]) {
        uint4 v = breg[i];
        if (do_gn) {
          int cb2 = (Cb[i] + ch * 32) * 2;
          float4 s01 = *(const float4*)(&shSB[cb2]);
          float4 s23 = *(const float4*)(&shSB[cb2 + 4]);
          float4 s45 = *(const float4*)(&shSB[cb2 + 8]);
          float4 s67 = *(const float4*)(&shSB[cb2 + 12]);
          u32 wv[4] = {v.x, v.y, v.z, v.w};
          float sc[8] = {s01.x, s01.z, s23.x, s23.z, s45.x, s45.z, s67.x, s67.z};
          float bi[8] = {s01.y, s01.w, s23.y, s23.w, s45.y, s45.w, s67.y, s67.w};
          bool kp = Keep[i];
          u32 ow[4];
#pragma unroll
          for (int jj = 0; jj < 4; ++jj) {
            float f0 = bf2f((u16)(wv[jj] & 0xffff)) * sc[2 * jj] + bi[2 * jj];
            float f1 = bf2f((u16)(wv[jj] >> 16)) * sc[2 * jj + 1] + bi[2 * jj + 1];
            f0 = kp ? fmaxf(f0, 0.f) : 0.f;
            f1 = kp ? fmaxf(f1, 0.f) : 0.f;
            ow[jj] = pack2(f0, f1);
          }
          v.x = ow[0]; v.y = ow[1]; v.z = ow[2]; v.w = ow[3];
        }
        *(uint4*)(Btile + Lo[i]) = v;
      }
    }
    __syncthreads();
    if (ch < 7) {  // prefetch next chunk's staging data into registers
#pragma unroll
      for (int i = 0; i < 3; ++i)
        if (Uok[i]) breg[i] = *(const uint4*)(Pptr[i] + (ch + 1) * 32);
    }
#pragma unroll
    for (int tap = 0; tap < 9; ++tap) {
      int kt = ch * 9 + tap;
      if (kt < 71) {  // prefetch A(kt+1) -> other register buffer
        const u16* wn_ = Wb + (long)(kt + 1) * 4096;
#pragma unroll
        for (int mi = 0; mi < 4; ++mi)
          areg[(tap + 1) & 1][mi] = *(const bf16x8*)(wn_ + mi * 512);
      }
      int dy = tap / 3, dx = tap - dy * 3;
      int bb = bcol + dy * 144 + dx * 8;
#pragma unroll
      for (int ni = 0; ni < 4; ++ni) {
        bf16x8 b = *(const bf16x8*)(Btile + bb + ni * 144);
#pragma unroll
        for (int mi = 0; mi < 4; ++mi)
          acc[mi][ni] =
              __builtin_amdgcn_mfma_f32_16x16x32_bf16(areg[tap & 1][mi], b, acc[mi][ni], 0, 0, 0);
      }
    }
#pragma unroll
    for (int mi = 0; mi < 4; ++mi) areg[0][mi] = areg[1][mi];  // carry to next chunk
  }
  // epilogue: store raw bf16 NHWC + group stats
  if (t < 32) sred[t] = 0.f;
  __syncthreads();
  long pebase = (long)(pxb + (y0 + 1) * Wp + (x0 + col + 1)) * 256;
#pragma unroll
  for (int ni = 0; ni < 4; ++ni) {
    int row = wn * 4 + ni;
    if (y0 + row < H) {
#pragma unroll
      for (int mi = 0; mi < 4; ++mi) {
        f32x4 v = acc[mi][ni];
        int o = mo * 128 + wm * 64 + mi * 16 + quad * 4;
        uint2 pk;
        pk.x = pack2(v[0], v[1]);
        pk.y = pack2(v[2], v[3]);
        *(uint2*)(Yraw + pebase + (long)row * Wp * 256 + o) = pk;
      }
    }
  }
#pragma unroll
  for (int mi = 0; mi < 4; ++mi) {
    float s1 = 0.f, s2 = 0.f;
#pragma unroll
    for (int ni = 0; ni < 4; ++ni) {
      if (y0 + wn * 4 + ni < H) {
        f32x4 v = acc[mi][ni];
#pragma unroll
        for (int r2 = 0; r2 < 4; ++r2) { float f = v[r2]; s1 += f; s2 += f * f; }
      }
    }
#pragma unroll
    for (int m = 1; m < 16; m <<= 1) { s1 += __shfl_xor(s1, m); s2 += __shfl_xor(s2, m); }
    if (col == 0) {
      int g = (wm * 64 + mi * 16 + quad * 4) >> 3;
      atomicAdd(&sred[g * 2], s1);
      atomicAdd(&sred[g * 2 + 1], s2);
    }
  }
  __syncthreads();
  if (t < 32) atomicAdd(&stats[(lvl * 32 + mo * 16 + (t >> 1)) * 2 + (t & 1)], sred[t]);
}

// ---------------- GN + ReLU elementwise via (scale,bias), in-place ----------------
__global__ void gn_relu(u16* __restrict__ buf, long tstride,
                        const float* __restrict__ scaleb, int sb_ts) {
  int i = blockIdx.x * 256 + threadIdx.x;
  int tw = i / 1745920;            // 54560*32 per tower
  int j = i - tw * 1745920;
  buf += tw * tstride;
  const float* sbp = scaleb + (long)tw * sb_ts;
  int px = j >> 5, cg = j & 31, c0 = cg << 3;
  int lvl, sh, pxb, rem;
  if (px < 40960)      { lvl = 0; rem = px;         sh = 8; pxb = 0;     }
  else if (px < 51200) { lvl = 1; rem = px - 40960; sh = 7; pxb = 41796; }
  else if (px < 53760) { lvl = 2; rem = px - 51200; sh = 6; pxb = 52456; }
  else if (px < 54400) { lvl = 3; rem = px - 53760; sh = 5; pxb = 55228; }
  else                 { lvl = 4; rem = px - 54400; sh = 4; pxb = 55976; }
  int W = 1 << sh;
  int y = rem >> sh, x = rem & (W - 1);
  long adr = (long)(pxb + (y + 1) * (W + 2) + (x + 1)) * 256 + c0;
  uint4 rv = *(const uint4*)(buf + adr);
  const float* pc = sbp + (lvl * 256 + c0) * 2;
  float4 q0 = *(const float4*)(pc);
  float4 q1 = *(const float4*)(pc + 4);
  float4 q2 = *(const float4*)(pc + 8);
  float4 q3 = *(const float4*)(pc + 12);
  float sc[8] = {q0.x, q0.z, q1.x, q1.z, q2.x, q2.z, q3.x, q3.z};
  float bi[8] = {q0.y, q0.w, q1.y, q1.w, q2.y, q2.w, q3.y, q3.w};
  u32 w[4] = {rv.x, rv.y, rv.z, rv.w};
  u32 ow[4];
#pragma unroll
  for (int jj = 0; jj < 4; ++jj) {
    float v0 = fmaxf(bf2f((u16)(w[jj] & 0xffff)) * sc[2 * jj] + bi[2 * jj], 0.f);
    float v1 = fmaxf(bf2f((u16)(w[jj] >> 16)) * sc[2 * jj + 1] + bi[2 * jj + 1], 0.f);
    ow[jj] = pack2(v0, v1);
  }
  uint4 sv = {ow[0], ow[1], ow[2], ow[3]};
  *(uint4*)(buf + adr) = sv;
}

// ---------------- fused head conv: all 3 heads in one dispatch ----------------
__global__ __launch_bounds__(256, 2) void conv_head_fused(
    const u16* __restrict__ Xbase, long ACT, int htsel, const u16* __restrict__ Whead,
    float* __restrict__ out, const float* __restrict__ pcb, const float* __restrict__ ptb,
    const float* __restrict__ prb, const float* __restrict__ pmb,
    const float* __restrict__ sb, const float* __restrict__ sm) {
  __shared__ u16 Alds[3072];
  __shared__ u16 Blds[2048];
  int bx = blockIdx.x;
  int ht, r;
  if (htsel >= 0) { ht = htsel; r = bx; }
  else { ht = bx / 853; r = bx - ht * 853; }
  int mt, woff;
  const float* bias0;
  const float* scl;
  if (ht == 0)      { mt = 96; woff = 0;      bias0 = pcb; scl = sb; }
  else if (ht == 1) { mt = 16; woff = 221184; bias0 = prb; scl = sb; }
  else              { mt = 48; woff = 258048; bias0 = pmb; scl = sm; }
  const u16* Xn = Xbase + ((htsel >= 0) ? 0 : (long)ht * ACT);
  const u16* Wh = Whead + woff;
  int mt32 = mt * 32, MI = mt >> 4;
  int lvl, tloc, W, H, SX, pxb, npx;
  if (r < 640)      { lvl = 0; tloc = r;       W = 256; H = 160; SX = 4; pxb = 0;     npx = 40960; }
  else if (r < 800) { lvl = 1; tloc = r - 640; W = 128; H = 80;  SX = 3; pxb = 41796; npx = 10240; }
  else if (r < 840) { lvl = 2; tloc = r - 800; W = 64;  H = 40;  SX = 2; pxb = 52456; npx = 2560;  }
  else if (r < 850) { lvl = 3; tloc = r - 840; W = 32;  H = 20;  SX = 1; pxb = 55228; npx = 640;   }
  else              { lvl = 4; tloc = r - 850; W = 16;  H = 10;  SX = 0; pxb = 55976; npx = 160;   }
  int obm, obc = 0;
  if (ht == 0) {
    const int obms[5] = {0, 3276800, 4096000, 4300800, 4352000};
    const int obcs[5] = {4583040, 4624000, 4634240, 4636800, 4637440};
    obm = obms[lvl]; obc = obcs[lvl];
  } else if (ht == 1) {
    const int obms[5] = {4364800, 4528640, 4569600, 4579840, 4582400};
    obm = obms[lvl];
  } else {
    const int obms[5] = {4637600, 6112160, 6480800, 6572960, 6596000};
    obm = obms[lvl];
  }
  int Wp = W + 2;
  int ty = tloc >> SX, txi = tloc & ((1 << SX) - 1);
  int y0 = ty * 4, x0 = txi * 16;
  int t = threadIdx.x, lane = t & 63, wave = t >> 6;
  int quad = lane >> 4, col = lane & 15;
  bool edge = (y0 + 5 > H + 1);
  int rr = (t & 63) >> 4, cc = t & 15, gg = t >> 6;
  const u16* Xrow = Xn + (long)(pxb + (y0 + rr) * Wp + (x0 + cc)) * 256 + gg * 8;
  int aoff = quad * (mt * 8) + col * 8;
  int boff = quad * 512 + (wave * 16 + col) * 8;
  f32x4 acc[6] = {};
  for (int ch = 0; ch < 8; ++ch) {
#pragma unroll
    for (int tap = 0; tap < 9; ++tap) {
      int dy = tap / 3, dx = tap - dy * 3;
      const u16* ws = Wh + (ch * 9 + tap) * mt32;
      int ta = t * 8;
      if (ta < mt32) glds16(ws + ta, Alds + ta);
      int tb = ta + 2048;
      if (tb < mt32) glds16(ws + tb, Alds + tb);
      const u16* xsrc = Xrow + ch * 32 + (dy * Wp + dx) * 256;
      if (!edge) {
        glds16(xsrc, Blds + t * 8);
      } else {
        int yp = y0 + rr + dy;
        uint4 v = {0, 0, 0, 0};
        if (yp <= H + 1) v = *(const uint4*)xsrc;
        *(uint4*)(Blds + t * 8) = v;
      }
      __syncthreads();
      bf16x8 b = *(const bf16x8*)(Blds + boff);
#pragma unroll
      for (int mi = 0; mi < 6; ++mi) {
        if (mi < MI) {
          bf16x8 a = *(const bf16x8*)(Alds + aoff + mi * 128);
          acc[mi] = __builtin_amdgcn_mfma_f32_16x16x32_bf16(a, b, acc[mi], 0, 0, 0);
        }
      }
      __syncthreads();
    }
  }
  int y = y0 + wave;
  if (y < H) {
    float sc = scl[lvl];
    int x = x0 + col;
#pragma unroll
    for (int mi = 0; mi < 6; ++mi) {
      if (mi < MI) {
#pragma unroll
        for (int r2 = 0; r2 < 4; ++r2) {
          int o = mi * 16 + quad * 4 + r2;
          float v = acc[mi][r2];
          if (ht == 0) {
            if (o < 80) out[obm + o * npx + y * W + x] = v + bias0[o];
            else if (o == 80) out[obc + y * W + x] = v + ptb[0];
          } else if (ht == 1) {
            if (o < 4) out[obm + o * npx + y * W + x] = expf((v + bias0[o]) * sc);
          } else {
            if (o < 36) out[obm + o * npx + y * W + x] = expf((v + bias0[o]) * sc);
          }
        }
      }
    }
  }
}

extern "C" void kernel_launch(void* const* d_in, const int* in_sizes, int n_in,
                              void* d_out, int out_size, void* d_ws, size_t ws_size,
                              hipStream_t stream) {
  const float* feat0 = (const float*)d_in[0];
  const float* feat1 = (const float*)d_in[1];
  const float* feat2 = (const float*)d_in[2];
  const float* feat3 = (const float*)d_in[3];
  const float* feat4 = (const float*)d_in[4];
  const float* cw = (const float*)d_in[5];
  const float* rw = (const float*)d_in[8];
  const float* mw = (const float*)d_in[11];
  const float* gmas[3] = {(const float*)d_in[6], (const float*)d_in[9], (const float*)d_in[12]};
  const float* btas[3] = {(const float*)d_in[7], (const float*)d_in[10], (const float*)d_in[13]};
  const float* pcw = (const float*)d_in[14];
  const float* pcb = (const float*)d_in[15];
  const float* prw = (const float*)d_in[16];
  const float* prb = (const float*)d_in[17];
  const float* pmw = (const float*)d_in[18];
  const float* pmb = (const float*)d_in[19];
  const float* ptw = (const float*)d_in[20];
  const float* ptb = (const float*)d_in[21];
  const float* sb = (const float*)d_in[22];
  const float* sm = (const float*)d_in[23];
  float* out = (float*)d_out;

  const long ACT = 14385152;         // u16 elems per tower activation buffer
  const long ACTB = 28770304;        // bytes
  const long WTS = 14893056;         // bytes of converted weights
  char* base = (char*)d_ws;
  u16* wts = (u16*)base;

  // fused layout: wts | X3 (3) | Y3 (3) | stats (3840 B) | scaleb (30720 B) | 64 KB slack
  size_t need_fused = WTS + 6 * (size_t)ACTB + 3840 + 30720 + 65536;

  convert_weights<<<29088, 256, 0, stream>>>(cw, rw, mw, pcw, prw, pmw, ptw, wts);

  if (ws_size >= need_fused) {
    u16* X = (u16*)(base + WTS);
    u16* Y = (u16*)(base + WTS + 3 * ACTB);
    float* stats = (float*)(base + WTS + 6 * ACTB);
    float* scaleb = (float*)(base + WTS + 6 * ACTB + 3840);
    halo_zero<<<612, 256, 0, stream>>>(X, Y, ACT, 3);
    feat_to_nhwc<<<3412, 256, 0, stream>>>(feat0, feat1, feat2, feat3, feat4, X, ACT, 1);
    for (int s = 0; s < 4; ++s) {
      u16* in = (s & 1) ? Y : X;
      u16* ot = (s & 1) ? X : Y;
      long ints = (s == 0) ? 0 : ACT;  // s=0: all towers share the single staged input
      hipMemsetAsync(stats, 0, 3840, stream);
      conv_tower<<<2568, 256, 0, stream>>>(in, ints, wts + s * 589824, 4 * 589824, ot, ACT,
                                           stats, 320, scaleb, 2560, s > 0);
      finalize_stats<<<15, 256, 0, stream>>>(stats, 320,
                                             gmas[0] + s * 256, gmas[1] + s * 256, gmas[2] + s * 256,
                                             btas[0] + s * 256, btas[1] + s * 256, btas[2] + s * 256,
                                             scaleb, 2560, 3);
    }
    // towers s0->Y, s1->X, s2->Y, s3->X; normalize s3 output in X, then heads
    gn_relu<<<20460, 256, 0, stream>>>(X, ACT, scaleb, 2560);
    conv_head_fused<<<2559, 256, 0, stream>>>(X, ACT, -1, wts + 7077888, out,
                                              pcb, ptb, prb, pmb, sb, sm);
  } else {
    // -------- fallback: sequential towers --------
    u16* bufA = (u16*)(base + WTS);
    u16* bufB = (u16*)(base + WTS + ACTB);
    float* stats = (float*)(base + WTS + 2 * ACTB);
    float* scaleb = (float*)(base + WTS + 2 * ACTB + 1280);
    halo_zero<<<204, 256, 0, stream>>>(bufA, bufB, 0, 1);
    for (int tw = 0; tw < 3; ++tw) {
      feat_to_nhwc<<<3412, 256, 0, stream>>>(feat0, feat1, feat2, feat3, feat4, bufA, 0, 1);
      for (int s = 0; s < 4; ++s) {
        u16* in = (s & 1) ? bufB : bufA;
        u16* ot = (s & 1) ? bufA : bufB;
        hipMemsetAsync(stats, 0, 1280, stream);
        conv_tower<<<856, 256, 0, stream>>>(in, 0, wts + (tw * 4 + s) * 589824, 0, ot, 0,
                                            stats, 0, scaleb, 0, s > 0);
        finalize_stats<<<5, 256, 0, stream>>>(stats, 0,
                                              gmas[tw] + s * 256, gmas[tw] + s * 256, gmas[tw] + s * 256,
                                              btas[tw] + s * 256, btas[tw] + s * 256, btas[tw] + s * 256,
                                              scaleb, 0, 1);
      }
      // towers: s0->B, s1->A, s2->B, s3->A
      gn_relu<<<6820, 256, 0, stream>>>(bufA, 0, scaleb, 0);
      conv_head_fused<<<853, 256, 0, stream>>>(bufA, 0, tw, wts + 7077888, out,
                                               pcb, ptb, prb, pmb, sb, sm);
    }
  }
}

// Round 7
// 1081.036 us; speedup vs baseline: 1.5657x; 1.0448x over previous
//
#include <hip/hip_runtime.h>

typedef unsigned short u16;
typedef unsigned int u32;
typedef short bf16x8 __attribute__((ext_vector_type(8)));
typedef float f32x4 __attribute__((ext_vector_type(4)));

__device__ __forceinline__ float bf2f(u16 u) {
  u32 x = ((u32)u) << 16;
  float f;
  __builtin_memcpy(&f, &x, 4);
  return f;
}
__device__ __forceinline__ u16 f2bf(float f) {
  u32 x;
  __builtin_memcpy(&x, &f, 4);
  u32 r = x + 0x7FFFu + ((x >> 16) & 1u);
  return (u16)(r >> 16);
}
// pack two fp32 -> bf16x2 (round-to-nearest-half-up): 2 adds + v_perm
__device__ __forceinline__ u32 pack2(float f0, float f1) {
  u32 a, b;
  __builtin_memcpy(&a, &f0, 4);
  __builtin_memcpy(&b, &f1, 4);
  a += 0x8000u;
  b += 0x8000u;
  return __builtin_amdgcn_perm(b, a, 0x07060302);
}
// async global->LDS, 16B per lane. LDS dest must be wave-uniform base + lane*16.
__device__ __forceinline__ void glds16(const u16* g, u16* l) {
  __builtin_amdgcn_global_load_lds((const __attribute__((address_space(1))) u32*)g,
                                   (__attribute__((address_space(3))) u32*)l, 16, 0, 0);
}

// ---------------- geometry ----------------
// levels: W {256,128,64,32,16} H {160,80,40,20,10}; padded (W+2)x(H+2) NHWC bf16
// padded pixel bases {0, 41796, 52456, 55228, 55976}; total 56192 px
// per-tower activation stride = 56192*256 = 14,385,152 u16 elements

// ---------------- weight conversion ----------------
// tower layout per conv (A-fragment order, for direct global->reg loads):
//   [mo(2)][kt(72)][wm(2)][mi(4)][lane(64)][j(8)]  (589824 elems)
//   kt = ch*9 + ti where ti = dx*3+dy (dx-major tap order for B row caching!)
//   element = W[o = mo*128+wm*64+mi*16+(lane&15)][c = (kt/9)*32+(lane>>4)*8+j][tap = dy*3+dx]
// head layout per (chunk,tap): [g(4)][o(MT)][c8(8)]  (MT: cls 96, reg 16, msk 48)
__global__ void convert_weights(const float* __restrict__ cw, const float* __restrict__ rw,
                                const float* __restrict__ mw, const float* __restrict__ pc,
                                const float* __restrict__ pr, const float* __restrict__ pm,
                                const float* __restrict__ pt, u16* __restrict__ dst) {
  int e = blockIdx.x * 256 + threadIdx.x;
  if (e >= 7446528) return;
  float v = 0.f;
  if (e < 7077888) {
    int conv = e / 589824, r = e % 589824;
    int mo = r / 294912;
    int r2 = r - mo * 294912;
    int kt = r2 >> 12;
    int r3 = r2 & 4095;
    int wm = r3 >> 11;
    int mi = (r3 >> 9) & 3;
    int l = (r3 >> 3) & 63;
    int j = r3 & 7;
    int ch = kt / 9, ti = kt - ch * 9;
    int dxs = ti / 3, dys = ti - dxs * 3;
    int tap = dys * 3 + dxs;  // source tap index (dy*3+dx)
    int o = mo * 128 + wm * 64 + mi * 16 + (l & 15);
    int c = ch * 32 + (l >> 4) * 8 + j;
    const float* s = (conv < 4) ? cw : (conv < 8) ? rw : mw;
    int si = conv & 3;
    v = s[((si * 256 + o) * 256 + c) * 9 + tap];
  } else {
    int e2 = e - 7077888;
    if (e2 < 221184) {  // cls head, MT=96 (80 cls + 1 ctr + pad)
      int chunk = e2 / 27648, r = e2 % 27648;
      int tap = r / 3072, r2 = r % 3072;
      int g = r2 / 768;
      int o = (r2 - g * 768) >> 3;
      int c = chunk * 32 + g * 8 + (r2 & 7);
      if (o < 80) v = pc[(o * 256 + c) * 9 + tap];
      else if (o == 80) v = pt[c * 9 + tap];
    } else if (e2 < 258048) {  // reg head, MT=16
      int e3 = e2 - 221184;
      int chunk = e3 / 4608, r = e3 % 4608;
      int tap = r / 512, r2 = r % 512;
      int g = r2 >> 7;
      int o = (r2 >> 3) & 15;
      int c = chunk * 32 + g * 8 + (r2 & 7);
      if (o < 4) v = pr[(o * 256 + c) * 9 + tap];
    } else {  // msk head, MT=48
      int e3 = e2 - 258048;
      int chunk = e3 / 13824, r = e3 % 13824;
      int tap = r / 1536, r2 = r % 1536;
      int g = r2 / 384;
      int o = (r2 - g * 384) >> 3;
      int c = chunk * 32 + g * 8 + (r2 & 7);
      if (o < 36) v = pm[(o * 256 + c) * 9 + tap];
    }
  }
  dst[e] = f2bf(v);
}

// ---------------- halo zero: clear 1-px border of padded buffers ----------------
__global__ void halo_zero(u16* __restrict__ X, u16* __restrict__ Y, long ACT, int ntw) {
  int i = blockIdx.x * 256 + threadIdx.x;
  int rep = i / 26112;         // 1632*16
  int j = i - rep * 26112;
  if (rep >= 2 * ntw) return;
  int hp = j >> 4, sub = j & 15;
  int Wp, Hp, pxb, h;
  if (hp < 836)       { Wp = 258; Hp = 162; pxb = 0;     h = hp; }
  else if (hp < 1256) { Wp = 130; Hp = 82;  pxb = 41796; h = hp - 836; }
  else if (hp < 1468) { Wp = 66;  Hp = 42;  pxb = 52456; h = hp - 1256; }
  else if (hp < 1576) { Wp = 34;  Hp = 22;  pxb = 55228; h = hp - 1468; }
  else                { Wp = 18;  Hp = 12;  pxb = 55976; h = hp - 1576; }
  int y, x;
  if (h < Wp)          { y = 0;      x = h; }
  else if (h < 2 * Wp) { y = Hp - 1; x = h - Wp; }
  else {
    int rr = h - 2 * Wp;
    y = 1 + (rr >> 1);
    x = (rr & 1) ? (Wp - 1) : 0;
  }
  u16* buf = (rep < ntw) ? (X + rep * ACT) : (Y + (rep - ntw) * ACT);
  long adr = (long)(pxb + y * Wp + x) * 256 + sub * 16;
  uint4 z = {0, 0, 0, 0};
  *(uint4*)(buf + adr) = z;
  *(uint4*)(buf + adr + 8) = z;
}

// ---------------- feat NCHW fp32 -> padded NHWC bf16 ----------------
__global__ void feat_to_nhwc(const float* __restrict__ f0, const float* __restrict__ f1,
                             const float* __restrict__ f2, const float* __restrict__ f3,
                             const float* __restrict__ f4, u16* __restrict__ dst,
                             long tstride, int nrep) {
  __shared__ float lds[64 * 65];
  int bx = blockIdx.x;
  int tile = bx >> 2, c0 = (bx & 3) * 64;
  int tl, sh, pxb, npx;
  const float* src;
  if (tile < 640)      { tl = tile;       sh = 8; pxb = 0;     npx = 40960; src = f0; }
  else if (tile < 800) { tl = tile - 640; sh = 7; pxb = 41796; npx = 10240; src = f1; }
  else if (tile < 840) { tl = tile - 800; sh = 6; pxb = 52456; npx = 2560;  src = f2; }
  else if (tile < 850) { tl = tile - 840; sh = 5; pxb = 55228; npx = 640;   src = f3; }
  else                 { tl = tile - 850; sh = 4; pxb = 55976; npx = 160;   src = f4; }
  int W = 1 << sh, Wp = W + 2;
  int px0 = tl * 64;
  int t = threadIdx.x;
  {
    int cc = (t >> 6) * 16, px = t & 63;
    bool ok = (px0 + px) < npx;
#pragma unroll
    for (int j = 0; j < 16; ++j) {
      float v = ok ? src[(c0 + cc + j) * npx + px0 + px] : 0.f;
      lds[(cc + j) * 65 + px] = v;
    }
  }
  __syncthreads();
  {
    int px = t >> 2, cL = (t & 3) * 16;
    int pxi = px0 + px;
    if (pxi < npx) {
      int y = pxi >> sh, x = pxi & (W - 1);
      u32 w[8];
#pragma unroll
      for (int j = 0; j < 8; ++j)
        w[j] = pack2(lds[(cL + 2 * j) * 65 + px], lds[(cL + 2 * j + 1) * 65 + px]);
      long adr = (long)(pxb + (y + 1) * Wp + (x + 1)) * 256 + c0 + cL;
      uint4 v0 = {w[0], w[1], w[2], w[3]}, v1 = {w[4], w[5], w[6], w[7]};
      for (int r = 0; r < nrep; ++r) {
        *(uint4*)(dst + r * tstride + adr) = v0;
        *(uint4*)(dst + r * tstride + adr + 8) = v1;
      }
    }
  }
}

// ---------------- finalize GN stats -> per-channel (scale, bias) ----------------
__global__ void finalize_stats(const float* __restrict__ stats, int st_ts,
                               const float* __restrict__ g0, const float* __restrict__ g1,
                               const float* __restrict__ g2, const float* __restrict__ b0,
                               const float* __restrict__ b1, const float* __restrict__ b2,
                               float* __restrict__ scaleb, int sb_ts, int ntw) {
  int i = blockIdx.x * 256 + threadIdx.x;
  if (i >= ntw * 1280) return;
  int tw = i / 1280, r = i - tw * 1280, lvl = r >> 8, c = r & 255, g = c >> 3;
  float cnt = (lvl == 0) ? 327680.f : (lvl == 1) ? 81920.f
              : (lvl == 2) ? 20480.f : (lvl == 3) ? 5120.f : 1280.f;
  float s1 = stats[tw * st_ts + (lvl * 32 + g) * 2];
  float s2 = stats[tw * st_ts + (lvl * 32 + g) * 2 + 1];
  float mean = s1 / cnt;
  float var = s2 / cnt - mean * mean;
  float inv = rsqrtf(fmaxf(var, 0.f) + 1e-5f);
  const float* ga = (tw == 0) ? g0 : (tw == 1) ? g1 : g2;
  const float* be = (tw == 0) ? b0 : (tw == 1) ? b1 : b2;
  float sc = inv * ga[c];
  scaleb[(long)tw * sb_ts + (lvl * 256 + c) * 2] = sc;
  scaleb[(long)tw * sb_ts + (lvl * 256 + c) * 2 + 1] = be[c] - mean * sc;
}

// ---------------- tower conv: 256->256 3x3, bf16 MFMA implicit GEMM ----------------
// 128 o x 128 px block, 4 waves, 4x4 frags. A global->registers in fragment order,
// double-buffered across K-steps (kt order = dx-major taps). B: plane-split LDS tile
// [q(4)][180px][8ch]; per dx, the 6 distinct row-fragments are cached in registers and
// reused across (dy,ni) -> LDS B reads halve (36 -> 18 b128 per wave per chunk), which
// lifts the ~40% LDS-throughput MfmaUtil ceiling to ~70%. Fused GN+ReLU on staging.
__global__ __launch_bounds__(256, 3) void conv_tower(
    const u16* __restrict__ Xn, long in_ts, const u16* __restrict__ Wt, long wt_ts,
    u16* __restrict__ Yraw, long out_ts, float* __restrict__ stats, int st_ts,
    const float* __restrict__ scaleb, int sb_ts, int do_gn) {
  __shared__ __align__(16) u16 Btile[5760];  // 4 planes x 180 px x 8 ch
  __shared__ float shSB[512];                // (scale,bias) per channel
  __shared__ float sred[32];
  int bx = blockIdx.x;
  int tw = bx / 856, r856 = bx - tw * 856;
  Xn += tw * in_ts; Wt += tw * wt_ts; Yraw += tw * out_ts; stats += tw * st_ts;
  int tile = r856 >> 1, mo = r856 & 1;
  int tloc, W, H, SX, pxb, lvl;
  if (tile < 320)      { lvl = 0; tloc = tile;       W = 256; H = 160; SX = 4; pxb = 0; }
  else if (tile < 400) { lvl = 1; tloc = tile - 320; W = 128; H = 80;  SX = 3; pxb = 41796; }
  else if (tile < 420) { lvl = 2; tloc = tile - 400; W = 64;  H = 40;  SX = 2; pxb = 52456; }
  else if (tile < 426) { lvl = 3; tloc = tile - 420; W = 32;  H = 20;  SX = 1; pxb = 55228; }
  else                 { lvl = 4; tloc = tile - 426; W = 16;  H = 10;  SX = 0; pxb = 55976; }
  int Wp = W + 2;
  int ty = tloc >> SX, txi = tloc & ((1 << SX) - 1);
  int y0 = ty * 8, x0 = txi * 16;
  int t = threadIdx.x, lane = t & 63, wave = t >> 6;
  int wm = wave >> 1, wn = wave & 1;
  int quad = lane >> 4, col = lane & 15;
  const u16* Xbase = Xn + (long)(pxb + y0 * Wp + x0) * 256;
  // A fragment base: [mo][kt][wm][mi][lane][8]
  const u16* Wb = Wt + (long)mo * 294912 + wm * 2048 + (long)lane * 8;
  int bcol = quad * 1440 + wn * 576 + col * 8;  // + r*144 per row, + dx*8 per shift
  if (do_gn) {
    float2 sv = *(const float2*)(scaleb + (long)tw * sb_ts + (lvl * 256 + t) * 2);
    *(float2*)(&shSB[t * 2]) = sv;
  }
  // per-thread staging map: 3 units of (plane q, pixel p)
  const u16* Pptr[3];
  int Lo[3], Cb[3];
  bool Uok[3], Keep[3];
#pragma unroll
  for (int i = 0; i < 3; ++i) {
    int u = t + i * 256;
    Uok[i] = u < 720;
    int q = u & 3, p = u >> 2;
    int py = p / 18, px = p - py * 18;
    Pptr[i] = Xbase + (long)(py * Wp + px) * 256 + q * 8;
    Lo[i] = q * 1440 + p * 8;
    Cb[i] = q * 8;
    int yg = y0 + py, xg = x0 + px;
    Keep[i] = (yg >= 1) && (yg <= H) && (xg >= 1) && (xg <= W);
  }
  uint4 breg[3];
#pragma unroll
  for (int i = 0; i < 3; ++i)
    if (Uok[i]) breg[i] = *(const uint4*)(Pptr[i]);  // ch=0 staging data
  bf16x8 areg[2][4];
#pragma unroll
  for (int mi = 0; mi < 4; ++mi) areg[0][mi] = *(const bf16x8*)(Wb + mi * 512);
  f32x4 acc[4][4] = {};
  for (int ch = 0; ch < 8; ++ch) {
    __syncthreads();  // shSB ready (ch=0) / all waves done reading previous Btile
#pragma unroll
    for (int i = 0; i < 3; ++i) {
      if (Uok[i]) {
        uint4 v = breg[i];
        if (do_gn) {
          int cb2 = (Cb[i] + ch * 32) * 2;
          float4 s01 = *(const float4*)(&shSB[cb2]);
          float4 s23 = *(const float4*)(&shSB[cb2 + 4]);
          float4 s45 = *(const float4*)(&shSB[cb2 + 8]);
          float4 s67 = *(const float4*)(&shSB[cb2 + 12]);
          u32 wv[4] = {v.x, v.y, v.z, v.w};
          float sc[8] = {s01.x, s01.z, s23.x, s23.z, s45.x, s45.z, s67.x, s67.z};
          float bi[8] = {s01.y, s01.w, s23.y, s23.w, s45.y, s45.w, s67.y, s67.w};
          bool kp = Keep[i];
          u32 ow[4];
#pragma unroll
          for (int jj = 0; jj < 4; ++jj) {
            float f0 = bf2f((u16)(wv[jj] & 0xffff)) * sc[2 * jj] + bi[2 * jj];
            float f1 = bf2f((u16)(wv[jj] >> 16)) * sc[2 * jj + 1] + bi[2 * jj + 1];
            f0 = kp ? fmaxf(f0, 0.f) : 0.f;
            f1 = kp ? fmaxf(f1, 0.f) : 0.f;
            ow[jj] = pack2(f0, f1);
          }
          v.x = ow[0]; v.y = ow[1]; v.z = ow[2]; v.w = ow[3];
        }
        *(uint4*)(Btile + Lo[i]) = v;
      }
    }
    __syncthreads();
    if (ch < 7) {  // prefetch next chunk's staging data into registers
#pragma unroll
      for (int i = 0; i < 3; ++i)
        if (Uok[i]) breg[i] = *(const uint4*)(Pptr[i] + (ch + 1) * 32);
    }
    bf16x8 brow[6];
#pragma unroll
    for (int ti = 0; ti < 9; ++ti) {
      int kt = ch * 9 + ti;
      int dxq = ti / 3, dyq = ti - dxq * 3;
      if (dyq == 0) {  // new dx: load the 6 distinct row fragments once
#pragma unroll
        for (int r = 0; r < 6; ++r)
          brow[r] = *(const bf16x8*)(Btile + bcol + r * 144 + dxq * 8);
      }
      if (kt < 71) {  // prefetch A(kt+1) -> other register buffer
        const u16* wn_ = Wb + (long)(kt + 1) * 4096;
#pragma unroll
        for (int mi = 0; mi < 4; ++mi)
          areg[(ti + 1) & 1][mi] = *(const bf16x8*)(wn_ + mi * 512);
      }
#pragma unroll
      for (int ni = 0; ni < 4; ++ni) {
        bf16x8 b = brow[dyq + ni];
#pragma unroll
        for (int mi = 0; mi < 4; ++mi)
          acc[mi][ni] =
              __builtin_amdgcn_mfma_f32_16x16x32_bf16(areg[ti & 1][mi], b, acc[mi][ni], 0, 0, 0);
      }
    }
#pragma unroll
    for (int mi = 0; mi < 4; ++mi) areg[0][mi] = areg[1][mi];  // carry to next chunk
  }
  // epilogue: store raw bf16 NHWC + group stats
  if (t < 32) sred[t] = 0.f;
  __syncthreads();
  long pebase = (long)(pxb + (y0 + 1) * Wp + (x0 + col + 1)) * 256;
#pragma unroll
  for (int ni = 0; ni < 4; ++ni) {
    int row = wn * 4 + ni;
    if (y0 + row < H) {
#pragma unroll
      for (int mi = 0; mi < 4; ++mi) {
        f32x4 v = acc[mi][ni];
        int o = mo * 128 + wm * 64 + mi * 16 + quad * 4;
        uint2 pk;
        pk.x = pack2(v[0], v[1]);
        pk.y = pack2(v[2], v[3]);
        *(uint2*)(Yraw + pebase + (long)row * Wp * 256 + o) = pk;
      }
    }
  }
#pragma unroll
  for (int mi = 0; mi < 4; ++mi) {
    float s1 = 0.f, s2 = 0.f;
#pragma unroll
    for (int ni = 0; ni < 4; ++ni) {
      if (y0 + wn * 4 + ni < H) {
        f32x4 v = acc[mi][ni];
#pragma unroll
        for (int r2 = 0; r2 < 4; ++r2) { float f = v[r2]; s1 += f; s2 += f * f; }
      }
    }
#pragma unroll
    for (int m = 1; m < 16; m <<= 1) { s1 += __shfl_xor(s1, m); s2 += __shfl_xor(s2, m); }
    if (col == 0) {
      int g = (wm * 64 + mi * 16 + quad * 4) >> 3;
      atomicAdd(&sred[g * 2], s1);
      atomicAdd(&sred[g * 2 + 1], s2);
    }
  }
  __syncthreads();
  if (t < 32) atomicAdd(&stats[(lvl * 32 + mo * 16 + (t >> 1)) * 2 + (t & 1)], sred[t]);
}

// ---------------- GN + ReLU elementwise via (scale,bias), in-place ----------------
__global__ void gn_relu(u16* __restrict__ buf, long tstride,
                        const float* __restrict__ scaleb, int sb_ts) {
  int i = blockIdx.x * 256 + threadIdx.x;
  int tw = i / 1745920;            // 54560*32 per tower
  int j = i - tw * 1745920;
  buf += tw * tstride;
  const float* sbp = scaleb + (long)tw * sb_ts;
  int px = j >> 5, cg = j & 31, c0 = cg << 3;
  int lvl, sh, pxb, rem;
  if (px < 40960)      { lvl = 0; rem = px;         sh = 8; pxb = 0;     }
  else if (px < 51200) { lvl = 1; rem = px - 40960; sh = 7; pxb = 41796; }
  else if (px < 53760) { lvl = 2; rem = px - 51200; sh = 6; pxb = 52456; }
  else if (px < 54400) { lvl = 3; rem = px - 53760; sh = 5; pxb = 55228; }
  else                 { lvl = 4; rem = px - 54400; sh = 4; pxb = 55976; }
  int W = 1 << sh;
  int y = rem >> sh, x = rem & (W - 1);
  long adr = (long)(pxb + (y + 1) * (W + 2) + (x + 1)) * 256 + c0;
  uint4 rv = *(const uint4*)(buf + adr);
  const float* pc = sbp + (lvl * 256 + c0) * 2;
  float4 q0 = *(const float4*)(pc);
  float4 q1 = *(const float4*)(pc + 4);
  float4 q2 = *(const float4*)(pc + 8);
  float4 q3 = *(const float4*)(pc + 12);
  float sc[8] = {q0.x, q0.z, q1.x, q1.z, q2.x, q2.z, q3.x, q3.z};
  float bi[8] = {q0.y, q0.w, q1.y, q1.w, q2.y, q2.w, q3.y, q3.w};
  u32 w[4] = {rv.x, rv.y, rv.z, rv.w};
  u32 ow[4];
#pragma unroll
  for (int jj = 0; jj < 4; ++jj) {
    float v0 = fmaxf(bf2f((u16)(w[jj] & 0xffff)) * sc[2 * jj] + bi[2 * jj], 0.f);
    float v1 = fmaxf(bf2f((u16)(w[jj] >> 16)) * sc[2 * jj + 1] + bi[2 * jj + 1], 0.f);
    ow[jj] = pack2(v0, v1);
  }
  uint4 sv = {ow[0], ow[1], ow[2], ow[3]};
  *(uint4*)(buf + adr) = sv;
}

// ---------------- fused head conv: all 3 heads in one dispatch ----------------
__global__ __launch_bounds__(256, 2) void conv_head_fused(
    const u16* __restrict__ Xbase, long ACT, int htsel, const u16* __restrict__ Whead,
    float* __restrict__ out, const float* __restrict__ pcb, const float* __restrict__ ptb,
    const float* __restrict__ prb, const float* __restrict__ pmb,
    const float* __restrict__ sb, const float* __restrict__ sm) {
  __shared__ u16 Alds[3072];
  __shared__ u16 Blds[2048];
  int bx = blockIdx.x;
  int ht, r;
  if (htsel >= 0) { ht = htsel; r = bx; }
  else { ht = bx / 853; r = bx - ht * 853; }
  int mt, woff;
  const float* bias0;
  const float* scl;
  if (ht == 0)      { mt = 96; woff = 0;      bias0 = pcb; scl = sb; }
  else if (ht == 1) { mt = 16; woff = 221184; bias0 = prb; scl = sb; }
  else              { mt = 48; woff = 258048; bias0 = pmb; scl = sm; }
  const u16* Xn = Xbase + ((htsel >= 0) ? 0 : (long)ht * ACT);
  const u16* Wh = Whead + woff;
  int mt32 = mt * 32, MI = mt >> 4;
  int lvl, tloc, W, H, SX, pxb, npx;
  if (r < 640)      { lvl = 0; tloc = r;       W = 256; H = 160; SX = 4; pxb = 0;     npx = 40960; }
  else if (r < 800) { lvl = 1; tloc = r - 640; W = 128; H = 80;  SX = 3; pxb = 41796; npx = 10240; }
  else if (r < 840) { lvl = 2; tloc = r - 800; W = 64;  H = 40;  SX = 2; pxb = 52456; npx = 2560;  }
  else if (r < 850) { lvl = 3; tloc = r - 840; W = 32;  H = 20;  SX = 1; pxb = 55228; npx = 640;   }
  else              { lvl = 4; tloc = r - 850; W = 16;  H = 10;  SX = 0; pxb = 55976; npx = 160;   }
  int obm, obc = 0;
  if (ht == 0) {
    const int obms[5] = {0, 3276800, 4096000, 4300800, 4352000};
    const int obcs[5] = {4583040, 4624000, 4634240, 4636800, 4637440};
    obm = obms[lvl]; obc = obcs[lvl];
  } else if (ht == 1) {
    const int obms[5] = {4364800, 4528640, 4569600, 4579840, 4582400};
    obm = obms[lvl];
  } else {
    const int obms[5] = {4637600, 6112160, 6480800, 6572960, 6596000};
    obm = obms[lvl];
  }
  int Wp = W + 2;
  int ty = tloc >> SX, txi = tloc & ((1 << SX) - 1);
  int y0 = ty * 4, x0 = txi * 16;
  int t = threadIdx.x, lane = t & 63, wave = t >> 6;
  int quad = lane >> 4, col = lane & 15;
  bool edge = (y0 + 5 > H + 1);
  int rr = (t & 63) >> 4, cc = t & 15, gg = t >> 6;
  const u16* Xrow = Xn + (long)(pxb + (y0 + rr) * Wp + (x0 + cc)) * 256 + gg * 8;
  int aoff = quad * (mt * 8) + col * 8;
  int boff = quad * 512 + (wave * 16 + col) * 8;
  f32x4 acc[6] = {};
  for (int ch = 0; ch < 8; ++ch) {
#pragma unroll
    for (int tap = 0; tap < 9; ++tap) {
      int dy = tap / 3, dx = tap - dy * 3;
      const u16* ws = Wh + (ch * 9 + tap) * mt32;
      int ta = t * 8;
      if (ta < mt32) glds16(ws + ta, Alds + ta);
      int tb = ta + 2048;
      if (tb < mt32) glds16(ws + tb, Alds + tb);
      const u16* xsrc = Xrow + ch * 32 + (dy * Wp + dx) * 256;
      if (!edge) {
        glds16(xsrc, Blds + t * 8);
      } else {
        int yp = y0 + rr + dy;
        uint4 v = {0, 0, 0, 0};
        if (yp <= H + 1) v = *(const uint4*)xsrc;
        *(uint4*)(Blds + t * 8) = v;
      }
      __syncthreads();
      bf16x8 b = *(const bf16x8*)(Blds + boff);
#pragma unroll
      for (int mi = 0; mi < 6; ++mi) {
        if (mi < MI) {
          bf16x8 a = *(const bf16x8*)(Alds + aoff + mi * 128);
          acc[mi] = __builtin_amdgcn_mfma_f32_16x16x32_bf16(a, b, acc[mi], 0, 0, 0);
        }
      }
      __syncthreads();
    }
  }
  int y = y0 + wave;
  if (y < H) {
    float sc = scl[lvl];
    int x = x0 + col;
#pragma unroll
    for (int mi = 0; mi < 6; ++mi) {
      if (mi < MI) {
#pragma unroll
        for (int r2 = 0; r2 < 4; ++r2) {
          int o = mi * 16 + quad * 4 + r2;
          float v = acc[mi][r2];
          if (ht == 0) {
            if (o < 80) out[obm + o * npx + y * W + x] = v + bias0[o];
            else if (o == 80) out[obc + y * W + x] = v + ptb[0];
          } else if (ht == 1) {
            if (o < 4) out[obm + o * npx + y * W + x] = expf((v + bias0[o]) * sc);
          } else {
            if (o < 36) out[obm + o * npx + y * W + x] = expf((v + bias0[o]) * sc);
          }
        }
      }
    }
  }
}

extern "C" void kernel_launch(void* const* d_in, const int* in_sizes, int n_in,
                              void* d_out, int out_size, void* d_ws, size_t ws_size,
                              hipStream_t stream) {
  const float* feat0 = (const float*)d_in[0];
  const float* feat1 = (const float*)d_in[1];
  const float* feat2 = (const float*)d_in[2];
  const float* feat3 = (const float*)d_in[3];
  const float* feat4 = (const float*)d_in[4];
  const float* cw = (const float*)d_in[5];
  const float* rw = (const float*)d_in[8];
  const float* mw = (const float*)d_in[11];
  const float* gmas[3] = {(const float*)d_in[6], (const float*)d_in[9], (const float*)d_in[12]};
  const float* btas[3] = {(const float*)d_in[7], (const float*)d_in[10], (const float*)d_in[13]};
  const float* pcw = (const float*)d_in[14];
  const float* pcb = (const float*)d_in[15];
  const float* prw = (const float*)d_in[16];
  const float* prb = (const float*)d_in[17];
  const float* pmw = (const float*)d_in[18];
  const float* pmb = (const float*)d_in[19];
  const float* ptw = (const float*)d_in[20];
  const float* ptb = (const float*)d_in[21];
  const float* sb = (const float*)d_in[22];
  const float* sm = (const float*)d_in[23];
  float* out = (float*)d_out;

  const long ACT = 14385152;         // u16 elems per tower activation buffer
  const long ACTB = 28770304;        // bytes
  const long WTS = 14893056;         // bytes of converted weights
  char* base = (char*)d_ws;
  u16* wts = (u16*)base;

  // fused layout: wts | X3 (3) | Y3 (3) | stats (3840 B) | scaleb (30720 B) | 64 KB slack
  size_t need_fused = WTS + 6 * (size_t)ACTB + 3840 + 30720 + 65536;

  convert_weights<<<29088, 256, 0, stream>>>(cw, rw, mw, pcw, prw, pmw, ptw, wts);

  if (ws_size >= need_fused) {
    u16* X = (u16*)(base + WTS);
    u16* Y = (u16*)(base + WTS + 3 * ACTB);
    float* stats = (float*)(base + WTS + 6 * ACTB);
    float* scaleb = (float*)(base + WTS + 6 * ACTB + 3840);
    halo_zero<<<612, 256, 0, stream>>>(X, Y, ACT, 3);
    feat_to_nhwc<<<3412, 256, 0, stream>>>(feat0, feat1, feat2, feat3, feat4, X, ACT, 1);
    for (int s = 0; s < 4; ++s) {
      u16* in = (s & 1) ? Y : X;
      u16* ot = (s & 1) ? X : Y;
      long ints = (s == 0) ? 0 : ACT;  // s=0: all towers share the single staged input
      hipMemsetAsync(stats, 0, 3840, stream);
      conv_tower<<<2568, 256, 0, stream>>>(in, ints, wts + s * 589824, 4 * 589824, ot, ACT,
                                           stats, 320, scaleb, 2560, s > 0);
      finalize_stats<<<15, 256, 0, stream>>>(stats, 320,
                                             gmas[0] + s * 256, gmas[1] + s * 256, gmas[2] + s * 256,
                                             btas[0] + s * 256, btas[1] + s * 256, btas[2] + s * 256,
                                             scaleb, 2560, 3);
    }
    // towers s0->Y, s1->X, s2->Y, s3->X; normalize s3 output in X, then heads
    gn_relu<<<20460, 256, 0, stream>>>(X, ACT, scaleb, 2560);
    conv_head_fused<<<2559, 256, 0, stream>>>(X, ACT, -1, wts + 7077888, out,
                                              pcb, ptb, prb, pmb, sb, sm);
  } else {
    // -------- fallback: sequential towers --------
    u16* bufA = (u16*)(base + WTS);
    u16* bufB = (u16*)(base + WTS + ACTB);
    float* stats = (float*)(base + WTS + 2 * ACTB);
    float* scaleb = (float*)(base + WTS + 2 * ACTB + 1280);
    halo_zero<<<204, 256, 0, stream>>>(bufA, bufB, 0, 1);
    for (int tw = 0; tw < 3; ++tw) {
      feat_to_nhwc<<<3412, 256, 0, stream>>>(feat0, feat1, feat2, feat3, feat4, bufA, 0, 1);
      for (int s = 0; s < 4; ++s) {
        u16* in = (s & 1) ? bufB : bufA;
        u16* ot = (s & 1) ? bufA : bufB;
        hipMemsetAsync(stats, 0, 1280, stream);
        conv_tower<<<856, 256, 0, stream>>>(in, 0, wts + (tw * 4 + s) * 589824, 0, ot, 0,
                                            stats, 0, scaleb, 0, s > 0);
        finalize_stats<<<5, 256, 0, stream>>>(stats, 0,
                                              gmas[tw] + s * 256, gmas[tw] + s * 256, gmas[tw] + s * 256,
                                              btas[tw] + s * 256, btas[tw] + s * 256, btas[tw] + s * 256,
                                              scaleb, 0, 1);
      }
      // towers: s0->B, s1->A, s2->B, s3->A
      gn_relu<<<6820, 256, 0, stream>>>(bufA, 0, scaleb, 0);
      conv_head_fused<<<853, 256, 0, stream>>>(bufA, 0, tw, wts + 7077888, out,
                                               pcb, ptb, prb, pmb, sb, sm);
    }
  }
}

// Round 8
// 1003.124 us; speedup vs baseline: 1.6873x; 1.0777x over previous
//
#include <hip/hip_runtime.h>

typedef unsigned short u16;
typedef unsigned int u32;
typedef short bf16x8 __attribute__((ext_vector_type(8)));
typedef float f32x4 __attribute__((ext_vector_type(4)));

__device__ __forceinline__ float bf2f(u16 u) {
  u32 x = ((u32)u) << 16;
  float f;
  __builtin_memcpy(&f, &x, 4);
  return f;
}
__device__ __forceinline__ u16 f2bf(float f) {
  u32 x;
  __builtin_memcpy(&x, &f, 4);
  u32 r = x + 0x7FFFu + ((x >> 16) & 1u);
  return (u16)(r >> 16);
}
// pack two fp32 -> bf16x2 (round-to-nearest-half-up): 2 adds + v_perm
__device__ __forceinline__ u32 pack2(float f0, float f1) {
  u32 a, b;
  __builtin_memcpy(&a, &f0, 4);
  __builtin_memcpy(&b, &f1, 4);
  a += 0x8000u;
  b += 0x8000u;
  return __builtin_amdgcn_perm(b, a, 0x07060302);
}

// ---------------- geometry ----------------
// levels: W {256,128,64,32,16} H {160,80,40,20,10}; padded (W+2)x(H+2) NHWC bf16
// padded pixel bases {0, 41796, 52456, 55228, 55976}; total 56192 px
// per-tower activation stride = 56192*256 = 14,385,152 u16 elements

// ---------------- weight conversion ----------------
// tower layout per conv (A-fragment order): [mo(2)][kt(72)][wm(2)][mi(4)][lane(64)][j(8)]
//   kt = ch*9 + ti, ti = dx*3+dy (dx-major for B row caching)
// head layout: [kt(72)][mi(MI)][lane(64)][j(8)] per head; cls MT=96 (80+ctr+pad),
//   reg MT=16 (4+pad), msk MT=48 (36+pad); offsets 0 / 221184 / 258048.
__global__ void convert_weights(const float* __restrict__ cw, const float* __restrict__ rw,
                                const float* __restrict__ mw, const float* __restrict__ pc,
                                const float* __restrict__ pr, const float* __restrict__ pm,
                                const float* __restrict__ pt, u16* __restrict__ dst) {
  int e = blockIdx.x * 256 + threadIdx.x;
  if (e >= 7446528) return;
  float v = 0.f;
  if (e < 7077888) {
    int conv = e / 589824, r = e % 589824;
    int mo = r / 294912;
    int r2 = r - mo * 294912;
    int kt = r2 >> 12;
    int r3 = r2 & 4095;
    int wm = r3 >> 11;
    int mi = (r3 >> 9) & 3;
    int l = (r3 >> 3) & 63;
    int j = r3 & 7;
    int ch = kt / 9, ti = kt - ch * 9;
    int dxs = ti / 3, dys = ti - dxs * 3;
    int tap = dys * 3 + dxs;
    int o = mo * 128 + wm * 64 + mi * 16 + (l & 15);
    int c = ch * 32 + (l >> 4) * 8 + j;
    const float* s = (conv < 4) ? cw : (conv < 8) ? rw : mw;
    int si = conv & 3;
    v = s[((si * 256 + o) * 256 + c) * 9 + tap];
  } else {
    int e2 = e - 7077888;
    int kt, r2, mi, mtsel;
    const float* src = nullptr;
    int olim = 0;
    bool ctr = false;
    if (e2 < 221184) {        // cls MT=96
      kt = e2 / 3072; r2 = e2 % 3072; mi = r2 / 512; r2 %= 512;
      src = pc; olim = 80; ctr = true;
    } else if (e2 < 258048) { // reg MT=16
      int e3 = e2 - 221184;
      kt = e3 / 512; r2 = e3 % 512; mi = 0;
      src = pr; olim = 4;
    } else {                  // msk MT=48
      int e3 = e2 - 258048;
      kt = e3 / 1536; r2 = e3 % 1536; mi = r2 / 512; r2 %= 512;
      src = pm; olim = 36;
    }
    int l = r2 >> 3, j = r2 & 7;
    int ch = kt / 9, ti = kt - ch * 9;
    int dxs = ti / 3, dys = ti - dxs * 3;
    int tap = dys * 3 + dxs;
    int o = mi * 16 + (l & 15);
    int c = ch * 32 + (l >> 4) * 8 + j;
    if (o < olim) v = src[(o * 256 + c) * 9 + tap];
    else if (ctr && o == 80) v = pt[c * 9 + tap];
    (void)mtsel;
  }
  dst[e] = f2bf(v);
}

// ---------------- halo zero: clear 1-px border of padded buffers ----------------
__global__ void halo_zero(u16* __restrict__ X, u16* __restrict__ Y, long ACT, int ntw) {
  int i = blockIdx.x * 256 + threadIdx.x;
  int rep = i / 26112;         // 1632*16
  int j = i - rep * 26112;
  if (rep >= 2 * ntw) return;
  int hp = j >> 4, sub = j & 15;
  int Wp, Hp, pxb, h;
  if (hp < 836)       { Wp = 258; Hp = 162; pxb = 0;     h = hp; }
  else if (hp < 1256) { Wp = 130; Hp = 82;  pxb = 41796; h = hp - 836; }
  else if (hp < 1468) { Wp = 66;  Hp = 42;  pxb = 52456; h = hp - 1256; }
  else if (hp < 1576) { Wp = 34;  Hp = 22;  pxb = 55228; h = hp - 1468; }
  else                { Wp = 18;  Hp = 12;  pxb = 55976; h = hp - 1576; }
  int y, x;
  if (h < Wp)          { y = 0;      x = h; }
  else if (h < 2 * Wp) { y = Hp - 1; x = h - Wp; }
  else {
    int rr = h - 2 * Wp;
    y = 1 + (rr >> 1);
    x = (rr & 1) ? (Wp - 1) : 0;
  }
  u16* buf = (rep < ntw) ? (X + rep * ACT) : (Y + (rep - ntw) * ACT);
  long adr = (long)(pxb + y * Wp + x) * 256 + sub * 16;
  uint4 z = {0, 0, 0, 0};
  *(uint4*)(buf + adr) = z;
  *(uint4*)(buf + adr + 8) = z;
}

// ---------------- feat NCHW fp32 -> padded NHWC bf16 ----------------
__global__ void feat_to_nhwc(const float* __restrict__ f0, const float* __restrict__ f1,
                             const float* __restrict__ f2, const float* __restrict__ f3,
                             const float* __restrict__ f4, u16* __restrict__ dst,
                             long tstride, int nrep) {
  __shared__ float lds[64 * 65];
  int bx = blockIdx.x;
  int tile = bx >> 2, c0 = (bx & 3) * 64;
  int tl, sh, pxb, npx;
  const float* src;
  if (tile < 640)      { tl = tile;       sh = 8; pxb = 0;     npx = 40960; src = f0; }
  else if (tile < 800) { tl = tile - 640; sh = 7; pxb = 41796; npx = 10240; src = f1; }
  else if (tile < 840) { tl = tile - 800; sh = 6; pxb = 52456; npx = 2560;  src = f2; }
  else if (tile < 850) { tl = tile - 840; sh = 5; pxb = 55228; npx = 640;   src = f3; }
  else                 { tl = tile - 850; sh = 4; pxb = 55976; npx = 160;   src = f4; }
  int W = 1 << sh, Wp = W + 2;
  int px0 = tl * 64;
  int t = threadIdx.x;
  {
    int cc = (t >> 6) * 16, px = t & 63;
    bool ok = (px0 + px) < npx;
#pragma unroll
    for (int j = 0; j < 16; ++j) {
      float v = ok ? src[(c0 + cc + j) * npx + px0 + px] : 0.f;
      lds[(cc + j) * 65 + px] = v;
    }
  }
  __syncthreads();
  {
    int px = t >> 2, cL = (t & 3) * 16;
    int pxi = px0 + px;
    if (pxi < npx) {
      int y = pxi >> sh, x = pxi & (W - 1);
      u32 w[8];
#pragma unroll
      for (int j = 0; j < 8; ++j)
        w[j] = pack2(lds[(cL + 2 * j) * 65 + px], lds[(cL + 2 * j + 1) * 65 + px]);
      long adr = (long)(pxb + (y + 1) * Wp + (x + 1)) * 256 + c0 + cL;
      uint4 v0 = {w[0], w[1], w[2], w[3]}, v1 = {w[4], w[5], w[6], w[7]};
      for (int r = 0; r < nrep; ++r) {
        *(uint4*)(dst + r * tstride + adr) = v0;
        *(uint4*)(dst + r * tstride + adr + 8) = v1;
      }
    }
  }
}

// ---------------- finalize GN stats -> per-channel (scale, bias) ----------------
__global__ void finalize_stats(const float* __restrict__ stats, int st_ts,
                               const float* __restrict__ g0, const float* __restrict__ g1,
                               const float* __restrict__ g2, const float* __restrict__ b0,
                               const float* __restrict__ b1, const float* __restrict__ b2,
                               float* __restrict__ scaleb, int sb_ts, int ntw) {
  int i = blockIdx.x * 256 + threadIdx.x;
  if (i >= ntw * 1280) return;
  int tw = i / 1280, r = i - tw * 1280, lvl = r >> 8, c = r & 255, g = c >> 3;
  float cnt = (lvl == 0) ? 327680.f : (lvl == 1) ? 81920.f
              : (lvl == 2) ? 20480.f : (lvl == 3) ? 5120.f : 1280.f;
  float s1 = stats[tw * st_ts + (lvl * 32 + g) * 2];
  float s2 = stats[tw * st_ts + (lvl * 32 + g) * 2 + 1];
  float mean = s1 / cnt;
  float var = s2 / cnt - mean * mean;
  float inv = rsqrtf(fmaxf(var, 0.f) + 1e-5f);
  const float* ga = (tw == 0) ? g0 : (tw == 1) ? g1 : g2;
  const float* be = (tw == 0) ? b0 : (tw == 1) ? b1 : b2;
  float sc = inv * ga[c];
  scaleb[(long)tw * sb_ts + (lvl * 256 + c) * 2] = sc;
  scaleb[(long)tw * sb_ts + (lvl * 256 + c) * 2 + 1] = be[c] - mean * sc;
}

// ---------------- tower conv: 256->256 3x3, bf16 MFMA implicit GEMM ----------------
// 128 o x 128 px block, 4 waves, 4x4 frags. A global->registers (fragment order),
// double-buffered across K-steps. B: plane-split LDS tile, 6 row-frags cached in regs
// per dx. Fused GN+ReLU on staging. Measured plateau ~946 TF (m97-class structure).
__global__ __launch_bounds__(256, 3) void conv_tower(
    const u16* __restrict__ Xn, long in_ts, const u16* __restrict__ Wt, long wt_ts,
    u16* __restrict__ Yraw, long out_ts, float* __restrict__ stats, int st_ts,
    const float* __restrict__ scaleb, int sb_ts, int do_gn) {
  __shared__ __align__(16) u16 Btile[5760];  // 4 planes x 180 px x 8 ch
  __shared__ float shSB[512];                // (scale,bias) per channel
  __shared__ float sred[32];
  int bx = blockIdx.x;
  int tw = bx / 856, r856 = bx - tw * 856;
  Xn += tw * in_ts; Wt += tw * wt_ts; Yraw += tw * out_ts; stats += tw * st_ts;
  int tile = r856 >> 1, mo = r856 & 1;
  int tloc, W, H, SX, pxb, lvl;
  if (tile < 320)      { lvl = 0; tloc = tile;       W = 256; H = 160; SX = 4; pxb = 0; }
  else if (tile < 400) { lvl = 1; tloc = tile - 320; W = 128; H = 80;  SX = 3; pxb = 41796; }
  else if (tile < 420) { lvl = 2; tloc = tile - 400; W = 64;  H = 40;  SX = 2; pxb = 52456; }
  else if (tile < 426) { lvl = 3; tloc = tile - 420; W = 32;  H = 20;  SX = 1; pxb = 55228; }
  else                 { lvl = 4; tloc = tile - 426; W = 16;  H = 10;  SX = 0; pxb = 55976; }
  int Wp = W + 2;
  int ty = tloc >> SX, txi = tloc & ((1 << SX) - 1);
  int y0 = ty * 8, x0 = txi * 16;
  int t = threadIdx.x, lane = t & 63, wave = t >> 6;
  int wm = wave >> 1, wn = wave & 1;
  int quad = lane >> 4, col = lane & 15;
  const u16* Xbase = Xn + (long)(pxb + y0 * Wp + x0) * 256;
  const u16* Wb = Wt + (long)mo * 294912 + wm * 2048 + (long)lane * 8;
  int bcol = quad * 1440 + wn * 576 + col * 8;
  if (do_gn) {
    float2 sv = *(const float2*)(scaleb + (long)tw * sb_ts + (lvl * 256 + t) * 2);
    *(float2*)(&shSB[t * 2]) = sv;
  }
  const u16* Pptr[3];
  int Lo[3], Cb[3];
  bool Uok[3], Keep[3];
#pragma unroll
  for (int i = 0; i < 3; ++i) {
    int u = t + i * 256;
    Uok[i] = u < 720;
    int q = u & 3, p = u >> 2;
    int py = p / 18, px = p - py * 18;
    Pptr[i] = Xbase + (long)(py * Wp + px) * 256 + q * 8;
    Lo[i] = q * 1440 + p * 8;
    Cb[i] = q * 8;
    int yg = y0 + py, xg = x0 + px;
    Keep[i] = (yg >= 1) && (yg <= H) && (xg >= 1) && (xg <= W);
  }
  uint4 breg[3];
#pragma unroll
  for (int i = 0; i < 3; ++i)
    if (Uok[i]) breg[i] = *(const uint4*)(Pptr[i]);
  bf16x8 areg[2][4];
#pragma unroll
  for (int mi = 0; mi < 4; ++mi) areg[0][mi] = *(const bf16x8*)(Wb + mi * 512);
  f32x4 acc[4][4] = {};
  for (int ch = 0; ch < 8; ++ch) {
    __syncthreads();
#pragma unroll
    for (int i = 0; i < 3; ++i) {
      if (Uok[i]) {
        uint4 v = breg[i];
        if (do_gn) {
          int cb2 = (Cb[i] + ch * 32) * 2;
          float4 s01 = *(const float4*)(&shSB[cb2]);
          float4 s23 = *(const float4*)(&shSB[cb2 + 4]);
          float4 s45 = *(const float4*)(&shSB[cb2 + 8]);
          float4 s67 = *(const float4*)(&shSB[cb2 + 12]);
          u32 wv[4] = {v.x, v.y, v.z, v.w};
          float sc[8] = {s01.x, s01.z, s23.x, s23.z, s45.x, s45.z, s67.x, s67.z};
          float bi[8] = {s01.y, s01.w, s23.y, s23.w, s45.y, s45.w, s67.y, s67.w};
          bool kp = Keep[i];
          u32 ow[4];
#pragma unroll
          for (int jj = 0; jj < 4; ++jj) {
            float f0 = bf2f((u16)(wv[jj] & 0xffff)) * sc[2 * jj] + bi[2 * jj];
            float f1 = bf2f((u16)(wv[jj] >> 16)) * sc[2 * jj + 1] + bi[2 * jj + 1];
            f0 = kp ? fmaxf(f0, 0.f) : 0.f;
            f1 = kp ? fmaxf(f1, 0.f) : 0.f;
            ow[jj] = pack2(f0, f1);
          }
          v.x = ow[0]; v.y = ow[1]; v.z = ow[2]; v.w = ow[3];
        }
        *(uint4*)(Btile + Lo[i]) = v;
      }
    }
    __syncthreads();
    if (ch < 7) {
#pragma unroll
      for (int i = 0; i < 3; ++i)
        if (Uok[i]) breg[i] = *(const uint4*)(Pptr[i] + (ch + 1) * 32);
    }
    bf16x8 brow[6];
#pragma unroll
    for (int ti = 0; ti < 9; ++ti) {
      int kt = ch * 9 + ti;
      int dxq = ti / 3, dyq = ti - dxq * 3;
      if (dyq == 0) {
#pragma unroll
        for (int r = 0; r < 6; ++r)
          brow[r] = *(const bf16x8*)(Btile + bcol + r * 144 + dxq * 8);
      }
      {  // prefetch A(kt+1); kt=71 over-read stays inside wts (next conv/head region)
        const u16* wn_ = Wb + (long)(kt + 1) * 4096;
#pragma unroll
        for (int mi = 0; mi < 4; ++mi)
          areg[(ti + 1) & 1][mi] = *(const bf16x8*)(wn_ + mi * 512);
      }
#pragma unroll
      for (int ni = 0; ni < 4; ++ni) {
        bf16x8 b = brow[dyq + ni];
#pragma unroll
        for (int mi = 0; mi < 4; ++mi)
          acc[mi][ni] =
              __builtin_amdgcn_mfma_f32_16x16x32_bf16(areg[ti & 1][mi], b, acc[mi][ni], 0, 0, 0);
      }
    }
#pragma unroll
    for (int mi = 0; mi < 4; ++mi) areg[0][mi] = areg[1][mi];
  }
  // epilogue: store raw bf16 NHWC + group stats
  if (t < 32) sred[t] = 0.f;
  __syncthreads();
  long pebase = (long)(pxb + (y0 + 1) * Wp + (x0 + col + 1)) * 256;
#pragma unroll
  for (int ni = 0; ni < 4; ++ni) {
    int row = wn * 4 + ni;
    if (y0 + row < H) {
#pragma unroll
      for (int mi = 0; mi < 4; ++mi) {
        f32x4 v = acc[mi][ni];
        int o = mo * 128 + wm * 64 + mi * 16 + quad * 4;
        uint2 pk;
        pk.x = pack2(v[0], v[1]);
        pk.y = pack2(v[2], v[3]);
        *(uint2*)(Yraw + pebase + (long)row * Wp * 256 + o) = pk;
      }
    }
  }
#pragma unroll
  for (int mi = 0; mi < 4; ++mi) {
    float s1 = 0.f, s2 = 0.f;
#pragma unroll
    for (int ni = 0; ni < 4; ++ni) {
      if (y0 + wn * 4 + ni < H) {
        f32x4 v = acc[mi][ni];
#pragma unroll
        for (int r2 = 0; r2 < 4; ++r2) { float f = v[r2]; s1 += f; s2 += f * f; }
      }
    }
#pragma unroll
    for (int m = 1; m < 16; m <<= 1) { s1 += __shfl_xor(s1, m); s2 += __shfl_xor(s2, m); }
    if (col == 0) {
      int g = (wm * 64 + mi * 16 + quad * 4) >> 3;
      atomicAdd(&sred[g * 2], s1);
      atomicAdd(&sred[g * 2 + 1], s2);
    }
  }
  __syncthreads();
  if (t < 32) atomicAdd(&stats[(lvl * 32 + mo * 16 + (t >> 1)) * 2 + (t & 1)], sred[t]);
}

// ---------------- fused head conv (tower-style): GN+ReLU on staging ----------------
// ht 0: cls(80)+ctr MT=96; ht 1: reg(4,exp) MT=16; ht 2: msk(36,exp) MT=48.
// 128-px tiles (428/head); 4 waves n-split: wave covers px-rows {2w,2w+1}; MI m-frags.
// A global->reg double-buffered; B plane-split Btile, 4 row-frags cached per dx.
__global__ __launch_bounds__(256, 3) void conv_head_fused(
    const u16* __restrict__ Xbase, long ACT, int htsel, const u16* __restrict__ Whead,
    float* __restrict__ out, const float* __restrict__ pcb, const float* __restrict__ ptb,
    const float* __restrict__ prb, const float* __restrict__ pmb,
    const float* __restrict__ sb, const float* __restrict__ sm,
    const float* __restrict__ scaleb, long sb_ts) {
  __shared__ __align__(16) u16 Btile[5760];
  __shared__ float shSB[512];
  int bx = blockIdx.x;
  int ht, r;
  if (htsel >= 0) { ht = htsel; r = bx; }
  else { ht = bx / 428; r = bx - ht * 428; }
  int MI, woff, mt32;
  const float* bias0;
  const float* scl;
  if (ht == 0)      { MI = 6; woff = 0;      mt32 = 3072; bias0 = pcb; scl = sb; }
  else if (ht == 1) { MI = 1; woff = 221184; mt32 = 512;  bias0 = prb; scl = sb; }
  else              { MI = 3; woff = 258048; mt32 = 1536; bias0 = pmb; scl = sm; }
  const u16* Xn = Xbase + ((htsel >= 0) ? 0 : (long)ht * ACT);
  int tloc, W, H, SX, pxb, lvl, npx;
  if (r < 320)      { lvl = 0; tloc = r;       W = 256; H = 160; SX = 4; pxb = 0;     npx = 40960; }
  else if (r < 400) { lvl = 1; tloc = r - 320; W = 128; H = 80;  SX = 3; pxb = 41796; npx = 10240; }
  else if (r < 420) { lvl = 2; tloc = r - 400; W = 64;  H = 40;  SX = 2; pxb = 52456; npx = 2560;  }
  else if (r < 426) { lvl = 3; tloc = r - 420; W = 32;  H = 20;  SX = 1; pxb = 55228; npx = 640;   }
  else              { lvl = 4; tloc = r - 426; W = 16;  H = 10;  SX = 0; pxb = 55976; npx = 160;   }
  int obm, obc = 0;
  if (ht == 0) {
    const int obms[5] = {0, 3276800, 4096000, 4300800, 4352000};
    const int obcs[5] = {4583040, 4624000, 4634240, 4636800, 4637440};
    obm = obms[lvl]; obc = obcs[lvl];
  } else if (ht == 1) {
    const int obms[5] = {4364800, 4528640, 4569600, 4579840, 4582400};
    obm = obms[lvl];
  } else {
    const int obms[5] = {4637600, 6112160, 6480800, 6572960, 6596000};
    obm = obms[lvl];
  }
  int Wp = W + 2;
  int ty = tloc >> SX, txi = tloc & ((1 << SX) - 1);
  int y0 = ty * 8, x0 = txi * 16;
  int t = threadIdx.x, lane = t & 63, wave = t >> 6;
  int quad = lane >> 4, col = lane & 15;
  const u16* Xb2 = Xn + (long)(pxb + y0 * Wp + x0) * 256;
  const u16* Wb = Whead + woff + (long)lane * 8;
  {
    float2 sv = *(const float2*)(scaleb + ht * sb_ts + (lvl * 256 + t) * 2);
    *(float2*)(&shSB[t * 2]) = sv;
  }
  const u16* Pptr[3];
  int Lo[3], Cb[3];
  bool Uok[3], Keep[3];
#pragma unroll
  for (int i = 0; i < 3; ++i) {
    int u = t + i * 256;
    Uok[i] = u < 720;
    int q = u & 3, p = u >> 2;
    int py = p / 18, px = p - py * 18;
    Pptr[i] = Xb2 + (long)(py * Wp + px) * 256 + q * 8;
    Lo[i] = q * 1440 + p * 8;
    Cb[i] = q * 8;
    int yg = y0 + py, xg = x0 + px;
    Keep[i] = (yg >= 1) && (yg <= H) && (xg >= 1) && (xg <= W);
  }
  uint4 breg[3];
#pragma unroll
  for (int i = 0; i < 3; ++i)
    if (Uok[i]) breg[i] = *(const uint4*)(Pptr[i]);
  bf16x8 areg[2][6];
#pragma unroll
  for (int mi = 0; mi < 6; ++mi)
    if (mi < MI) areg[0][mi] = *(const bf16x8*)(Wb + mi * 512);
  f32x4 acc[6][2] = {};
  int brbase = quad * 1440 + wave * 288 + col * 8;  // rows 2w.. , + r*144, + dx*8
  for (int ch = 0; ch < 8; ++ch) {
    __syncthreads();
#pragma unroll
    for (int i = 0; i < 3; ++i) {
      if (Uok[i]) {
        uint4 v = breg[i];
        int cb2 = (Cb[i] + ch * 32) * 2;
        float4 s01 = *(const float4*)(&shSB[cb2]);
        float4 s23 = *(const float4*)(&shSB[cb2 + 4]);
        float4 s45 = *(const float4*)(&shSB[cb2 + 8]);
        float4 s67 = *(const float4*)(&shSB[cb2 + 12]);
        u32 wv[4] = {v.x, v.y, v.z, v.w};
        float sc[8] = {s01.x, s01.z, s23.x, s23.z, s45.x, s45.z, s67.x, s67.z};
        float bi[8] = {s01.y, s01.w, s23.y, s23.w, s45.y, s45.w, s67.y, s67.w};
        bool kp = Keep[i];
        u32 ow[4];
#pragma unroll
        for (int jj = 0; jj < 4; ++jj) {
          float f0 = bf2f((u16)(wv[jj] & 0xffff)) * sc[2 * jj] + bi[2 * jj];
          float f1 = bf2f((u16)(wv[jj] >> 16)) * sc[2 * jj + 1] + bi[2 * jj + 1];
          f0 = kp ? fmaxf(f0, 0.f) : 0.f;
          f1 = kp ? fmaxf(f1, 0.f) : 0.f;
          ow[jj] = pack2(f0, f1);
        }
        v.x = ow[0]; v.y = ow[1]; v.z = ow[2]; v.w = ow[3];
        *(uint4*)(Btile + Lo[i]) = v;
      }
    }
    __syncthreads();
    if (ch < 7) {
#pragma unroll
      for (int i = 0; i < 3; ++i)
        if (Uok[i]) breg[i] = *(const uint4*)(Pptr[i] + (ch + 1) * 32);
    }
    bf16x8 brow[4];
#pragma unroll
    for (int ti = 0; ti < 9; ++ti) {
      int kt = ch * 9 + ti;
      int dxq = ti / 3, dyq = ti - dxq * 3;
      if (dyq == 0) {
#pragma unroll
        for (int rr = 0; rr < 4; ++rr)
          brow[rr] = *(const bf16x8*)(Btile + brbase + rr * 144 + dxq * 8);
      }
      {  // prefetch A(kt+1); over-read at kt=71 stays inside d_ws, unused
        const u16* wn_ = Wb + (long)(kt + 1) * mt32;
#pragma unroll
        for (int mi = 0; mi < 6; ++mi)
          if (mi < MI) areg[(ti + 1) & 1][mi] = *(const bf16x8*)(wn_ + mi * 512);
      }
#pragma unroll
      for (int ni = 0; ni < 2; ++ni) {
        bf16x8 b = brow[dyq + ni];
#pragma unroll
        for (int mi = 0; mi < 6; ++mi)
          if (mi < MI)
            acc[mi][ni] =
                __builtin_amdgcn_mfma_f32_16x16x32_bf16(areg[ti & 1][mi], b, acc[mi][ni], 0, 0, 0);
      }
    }
#pragma unroll
    for (int mi = 0; mi < 6; ++mi)
      if (mi < MI) areg[0][mi] = areg[1][mi];
  }
  // epilogue: bias (+scale/exp) -> fp32 NCHW
  float scv = scl[lvl];
  int x = x0 + col;
#pragma unroll
  for (int ni = 0; ni < 2; ++ni) {
    int y = y0 + 2 * wave + ni;
    if (y < H) {
#pragma unroll
      for (int mi = 0; mi < 6; ++mi) {
        if (mi < MI) {
#pragma unroll
          for (int r2 = 0; r2 < 4; ++r2) {
            int o = mi * 16 + quad * 4 + r2;
            float v = acc[mi][ni][r2];
            if (ht == 0) {
              if (o < 80) out[obm + o * npx + y * W + x] = v + bias0[o];
              else if (o == 80) out[obc + y * W + x] = v + ptb[0];
            } else if (ht == 1) {
              if (o < 4) out[obm + o * npx + y * W + x] = expf((v + bias0[o]) * scv);
            } else {
              if (o < 36) out[obm + o * npx + y * W + x] = expf((v + bias0[o]) * scv);
            }
          }
        }
      }
    }
  }
}

extern "C" void kernel_launch(void* const* d_in, const int* in_sizes, int n_in,
                              void* d_out, int out_size, void* d_ws, size_t ws_size,
                              hipStream_t stream) {
  const float* feat0 = (const float*)d_in[0];
  const float* feat1 = (const float*)d_in[1];
  const float* feat2 = (const float*)d_in[2];
  const float* feat3 = (const float*)d_in[3];
  const float* feat4 = (const float*)d_in[4];
  const float* cw = (const float*)d_in[5];
  const float* rw = (const float*)d_in[8];
  const float* mw = (const float*)d_in[11];
  const float* gmas[3] = {(const float*)d_in[6], (const float*)d_in[9], (const float*)d_in[12]};
  const float* btas[3] = {(const float*)d_in[7], (const float*)d_in[10], (const float*)d_in[13]};
  const float* pcw = (const float*)d_in[14];
  const float* pcb = (const float*)d_in[15];
  const float* prw = (const float*)d_in[16];
  const float* prb = (const float*)d_in[17];
  const float* pmw = (const float*)d_in[18];
  const float* pmb = (const float*)d_in[19];
  const float* ptw = (const float*)d_in[20];
  const float* ptb = (const float*)d_in[21];
  const float* sb = (const float*)d_in[22];
  const float* sm = (const float*)d_in[23];
  float* out = (float*)d_out;

  const long ACT = 14385152;         // u16 elems per tower activation buffer
  const long ACTB = 28770304;        // bytes
  const long WTS = 14893056;         // bytes of converted weights
  char* base = (char*)d_ws;
  u16* wts = (u16*)base;

  // fused layout: wts | X3 (3) | Y3 (3) | stats (3840 B) | scaleb (30720 B) | 64 KB slack
  size_t need_fused = WTS + 6 * (size_t)ACTB + 3840 + 30720 + 65536;

  convert_weights<<<29088, 256, 0, stream>>>(cw, rw, mw, pcw, prw, pmw, ptw, wts);

  if (ws_size >= need_fused) {
    u16* X = (u16*)(base + WTS);
    u16* Y = (u16*)(base + WTS + 3 * ACTB);
    float* stats = (float*)(base + WTS + 6 * ACTB);
    float* scaleb = (float*)(base + WTS + 6 * ACTB + 3840);
    halo_zero<<<612, 256, 0, stream>>>(X, Y, ACT, 3);
    feat_to_nhwc<<<3412, 256, 0, stream>>>(feat0, feat1, feat2, feat3, feat4, X, ACT, 1);
    for (int s = 0; s < 4; ++s) {
      u16* in = (s & 1) ? Y : X;
      u16* ot = (s & 1) ? X : Y;
      long ints = (s == 0) ? 0 : ACT;  // s=0: all towers share the single staged input
      hipMemsetAsync(stats, 0, 3840, stream);
      conv_tower<<<2568, 256, 0, stream>>>(in, ints, wts + s * 589824, 4 * 589824, ot, ACT,
                                           stats, 320, scaleb, 2560, s > 0);
      finalize_stats<<<15, 256, 0, stream>>>(stats, 320,
                                             gmas[0] + s * 256, gmas[1] + s * 256, gmas[2] + s * 256,
                                             btas[0] + s * 256, btas[1] + s * 256, btas[2] + s * 256,
                                             scaleb, 2560, 3);
    }
    // s=3 raw output is in X; heads apply GN+ReLU (s=3 scaleb) during staging
    conv_head_fused<<<1284, 256, 0, stream>>>(X, ACT, -1, wts + 7077888, out,
                                              pcb, ptb, prb, pmb, sb, sm, scaleb, 2560);
  } else {
    // -------- fallback: sequential towers --------
    u16* bufA = (u16*)(base + WTS);
    u16* bufB = (u16*)(base + WTS + ACTB);
    float* stats = (float*)(base + WTS + 2 * ACTB);
    float* scaleb = (float*)(base + WTS + 2 * ACTB + 1280);
    halo_zero<<<204, 256, 0, stream>>>(bufA, bufB, 0, 1);
    for (int tw = 0; tw < 3; ++tw) {
      feat_to_nhwc<<<3412, 256, 0, stream>>>(feat0, feat1, feat2, feat3, feat4, bufA, 0, 1);
      for (int s = 0; s < 4; ++s) {
        u16* in = (s & 1) ? bufB : bufA;
        u16* ot = (s & 1) ? bufA : bufB;
        hipMemsetAsync(stats, 0, 1280, stream);
        conv_tower<<<856, 256, 0, stream>>>(in, 0, wts + (tw * 4 + s) * 589824, 0, ot, 0,
                                            stats, 0, scaleb, 0, s > 0);
        finalize_stats<<<5, 256, 0, stream>>>(stats, 0,
                                              gmas[tw] + s * 256, gmas[tw] + s * 256, gmas[tw] + s * 256,
                                              btas[tw] + s * 256, btas[tw] + s * 256, btas[tw] + s * 256,
                                              scaleb, 0, 1);
      }
      // s=3 raw output in bufA; head applies GN via scaleb (sb_ts=0)
      conv_head_fused<<<428, 256, 0, stream>>>(bufA, 0, tw, wts + 7077888, out,
                                               pcb, ptb, prb, pmb, sb, sm, scaleb, 0);
    }
  }
}